// Round 7
// baseline (614.736 us; speedup 1.0000x reference)
//
#include <hip/hip_runtime.h>

#define N_NODES 100000
#define N_EDGES 1600000
#define D_IN 128
#define HID 64
#define N_LAYERS 5
#define D_OUT 32
#define N_GRAPHS 1000

#define LNB 32            // nodes per block in k_input (4 waves x 8)
#define LR 8              // nodes per thread in k_input
#define NSHARD 8          // histogram shards (XCD count)

typedef unsigned short ushort_t;
typedef unsigned int uint_t;
typedef __attribute__((ext_vector_type(8))) short short8;   // 8 bf16 (4 VGPRs)
typedef __attribute__((ext_vector_type(4))) float f32x4;    // MFMA accumulator

#define MFMA(a, b, c) __builtin_amdgcn_mfma_f32_16x16x32_bf16((a), (b), (c), 0, 0, 0)

// per-layer stride of the prepped weight fragment arrays (in shorts)
#define WSTRIDE (24 * 2 * 64 * 8)

__device__ __forceinline__ float fast_sigmoid(float x) {
    return __builtin_amdgcn_rcpf(1.0f + __expf(-x));
}
__device__ __forceinline__ float fast_tanh(float x) {
    return 1.0f - 2.0f * __builtin_amdgcn_rcpf(1.0f + __expf(2.0f * x));
}
// fp32 -> bf16 round-to-nearest-even
__device__ __forceinline__ ushort_t f2bf(float f) {
    uint_t u = __float_as_uint(f);
    return (ushort_t)((u + 0x7fffu + ((u >> 16) & 1u)) >> 16);
}
// load 8 consecutive floats, split each into bf16 hi + bf16 lo
__device__ __forceinline__ void split8(const float* p, short8& hi, short8& lo) {
    float4 u0 = *(const float4*)p;
    float4 u1 = *(const float4*)(p + 4);
#define SPL(ii, fv) { float f_ = (fv); ushort_t h_ = f2bf(f_); hi[ii] = (short)h_;          \
                      float r_ = f_ - __uint_as_float(((uint_t)h_) << 16); lo[ii] = (short)f2bf(r_); }
    SPL(0, u0.x) SPL(1, u0.y) SPL(2, u0.z) SPL(3, u0.w)
    SPL(4, u1.x) SPL(5, u1.y) SPL(6, u1.z) SPL(7, u1.w)
#undef SPL
}

// ---------------------------------------------------------------------------
// Weight prep: emit bf16 hi/lo MFMA B-fragments.
// Combined B matrix [k=64][col=384]:
//   col<192 : Wc[k][col]   = sum_q ggnn_w[l][k][q] * w_ih[col][q]   (input side)
//   col>=192: w_hh[col-192][k]                                       (hidden side)
// Fragment layout: idx = ((((lay*24+t)*2+s)*64+lane)*8+i,
//   k = s*32 + (lane>>4)*8 + i,  col = t*16 + (lane&15).
__global__ void k_prep(const float* __restrict__ ggnn_w,
                       const float* __restrict__ w_ih,
                       const float* __restrict__ w_hh,
                       short* __restrict__ Whi,
                       short* __restrict__ Wlo) {
    int t = blockIdx.x * blockDim.x + threadIdx.x;
    if (t >= N_LAYERS * WSTRIDE) return;
    int i    = t & 7;
    int lane = (t >> 3) & 63;
    int s    = (t >> 9) & 1;
    int tt   = (t >> 10) % 24;
    int lay  = (t >> 10) / 24;
    int k    = s * 32 + (lane >> 4) * 8 + i;
    int col  = tt * 16 + (lane & 15);
    float val;
    if (col < 192) {
        const float* wl = ggnn_w + ((size_t)lay * HID + k) * HID;
        const float* wi = w_ih + (size_t)col * HID;
        float acc = 0.0f;
#pragma unroll 8
        for (int q = 0; q < HID; ++q) acc = fmaf(wl[q], wi[q], acc);
        val = acc;
    } else {
        val = w_hh[(size_t)(col - 192) * HID + k];
    }
    ushort_t h_ = f2bf(val);
    float r_ = val - __uint_as_float(((uint_t)h_) << 16);
    Whi[t] = (short)h_;
    Wlo[t] = (short)f2bf(r_);
}

// ---------------------------------------------------------------------------
// CSR build — sharded histogram (shard = blockIdx&7)
__global__ void k_hist(const int* __restrict__ ei,
                       int* __restrict__ deg8,
                       int* __restrict__ eslot) {
    int e = blockIdx.x * blockDim.x + threadIdx.x;
    if (e >= N_EDGES) return;
    int s = blockIdx.x & (NSHARD - 1);
    eslot[e] = atomicAdd(&deg8[s * N_NODES + ei[N_EDGES + e]], 1);
}

#define SCHUNK 1024
// scan1: fold 8 shards -> total degree; convert deg8 in-place to shard-prefix.
__global__ __launch_bounds__(1024) void k_scan1(int* __restrict__ deg8,
                                                int* __restrict__ off,
                                                int* __restrict__ bsum) {
    __shared__ int buf[SCHUNK];
    int tid = threadIdx.x;
    int i = blockIdx.x * SCHUNK + tid;
    int tot = 0;
    if (i < N_NODES) {
        int pre[NSHARD];
#pragma unroll
        for (int s = 0; s < NSHARD; ++s) {
            pre[s] = tot;
            tot += deg8[s * N_NODES + i];
        }
#pragma unroll
        for (int s = 0; s < NSHARD; ++s) deg8[s * N_NODES + i] = pre[s];
    }
    buf[tid] = tot;
    __syncthreads();
    for (int s = 1; s < SCHUNK; s <<= 1) {
        int a = (tid >= s) ? buf[tid - s] : 0;
        __syncthreads();
        buf[tid] += a;
        __syncthreads();
    }
    if (i < N_NODES) off[i] = buf[tid] - tot;
    if (tid == SCHUNK - 1) bsum[blockIdx.x] = buf[tid];
}

__global__ void k_scan2(int* __restrict__ bsum, int* __restrict__ off, int nchunks) {
    if (blockIdx.x == 0 && threadIdx.x == 0) {
        int carry = 0;
        for (int b = 0; b < nchunks; ++b) {
            int t = bsum[b];
            bsum[b] = carry;
            carry += t;
        }
        off[N_NODES] = carry;
    }
}

__global__ void k_scan3(int* __restrict__ off, const int* __restrict__ bsum) {
    int i = blockIdx.x * blockDim.x + threadIdx.x;
    if (i < N_NODES) off[i] += bsum[i >> 10];
}

// place: pos = off[d] + shard_prefix[s][d] + slot_within_shard
__global__ void k_place(const int* __restrict__ ei,
                        const int* __restrict__ off,
                        const int* __restrict__ deg8,
                        const int* __restrict__ eslot,
                        int* __restrict__ csr) {
    int e = blockIdx.x * blockDim.x + threadIdx.x;
    if (e >= N_EDGES) return;
    int s = blockIdx.x & (NSHARD - 1);
    int d = ei[N_EDGES + e];
    __builtin_nontemporal_store(ei[e], &csr[off[d] + deg8[s * N_NODES + d] + eslot[e]]);
}

// ---------------------------------------------------------------------------
// x = node_embed @ W_in + b_in; writes fp32 h and bf16 shadow hb
__global__ __launch_bounds__(256) void k_input(const float* __restrict__ ne,
                                               const float* __restrict__ W_in,
                                               const float* __restrict__ b_in,
                                               float* __restrict__ h,
                                               ushort_t* __restrict__ hb) {
    __shared__ float sE[LNB][D_IN];            // 16 KB
    int tid = threadIdx.x;
    int j = tid & 63, w = tid >> 6;
    int nodeBase = blockIdx.x * LNB;
    {
        const float4* g = (const float4*)(ne + (size_t)nodeBase * D_IN);
        float4* l = (float4*)&sE[0][0];
        for (int i = tid; i < LNB * D_IN / 4; i += 256) l[i] = g[i];
    }
    __syncthreads();
    float acc[LR];
#pragma unroll
    for (int r = 0; r < LR; ++r) acc[r] = 0.0f;
#pragma unroll 4
    for (int k = 0; k < D_IN; ++k) {
        float wv = W_in[k * HID + j];
#pragma unroll
        for (int r = 0; r < LR; ++r)
            acc[r] = fmaf(sE[w * LR + r][k], wv, acc[r]);
    }
    float b = b_in[j];
#pragma unroll
    for (int r = 0; r < LR; ++r) {
        int n = nodeBase + w * LR + r;
        float v = acc[r] + b;
        h[(size_t)n * HID + j] = v;
        hb[(size_t)n * HID + j] = f2bf(v);
    }
}

// ---------------------------------------------------------------------------
// CSR gather, software-pipelined: csr prefetch distance 1, two 128B rows in
// flight per wave-iteration (16 edges/iter). lane = (q = lane>>3 slot,
// c = lane&7 chunk); 8 lanes x uint4 = one row. Reduce via 3 shfl_xor.
__global__ __launch_bounds__(256) void k_gather(const int* __restrict__ off,
                                                const int* __restrict__ csr,
                                                const ushort_t* __restrict__ hb,
                                                float* __restrict__ agg) {
    int t = blockIdx.x * blockDim.x + threadIdx.x;
    int n = t >> 6;
    int lane = t & 63;
    int q = lane >> 3, c = lane & 7;
    int beg = off[n], end = off[n + 1];
    float a[8];
#pragma unroll
    for (int x = 0; x < 8; ++x) a[x] = 0.f;
    if (beg < end) {
        int e1 = end - 1;
        int i = beg + q;
        int s0 = csr[min(i, e1)];
        int s1 = csr[min(i + 8, e1)];
        for (; i < end; i += 16) {
            const uint4 v0 = *(const uint4*)(hb + (size_t)s0 * HID + c * 8);
            const uint4 v1 = *(const uint4*)(hb + (size_t)s1 * HID + c * 8);
            s0 = csr[min(i + 16, e1)];
            s1 = csr[min(i + 24, e1)];
            // v0 slot (= i) is valid under loop condition; v1 slot may not be
            a[0] += __uint_as_float(v0.x << 16);
            a[1] += __uint_as_float(v0.x & 0xffff0000u);
            a[2] += __uint_as_float(v0.y << 16);
            a[3] += __uint_as_float(v0.y & 0xffff0000u);
            a[4] += __uint_as_float(v0.z << 16);
            a[5] += __uint_as_float(v0.z & 0xffff0000u);
            a[6] += __uint_as_float(v0.w << 16);
            a[7] += __uint_as_float(v0.w & 0xffff0000u);
            float m1 = (i + 8 < end) ? 1.0f : 0.0f;
            a[0] = fmaf(m1, __uint_as_float(v1.x << 16), a[0]);
            a[1] = fmaf(m1, __uint_as_float(v1.x & 0xffff0000u), a[1]);
            a[2] = fmaf(m1, __uint_as_float(v1.y << 16), a[2]);
            a[3] = fmaf(m1, __uint_as_float(v1.y & 0xffff0000u), a[3]);
            a[4] = fmaf(m1, __uint_as_float(v1.z << 16), a[4]);
            a[5] = fmaf(m1, __uint_as_float(v1.z & 0xffff0000u), a[5]);
            a[6] = fmaf(m1, __uint_as_float(v1.w << 16), a[6]);
            a[7] = fmaf(m1, __uint_as_float(v1.w & 0xffff0000u), a[7]);
        }
    }
#pragma unroll
    for (int x = 0; x < 8; ++x) {
        a[x] += __shfl_xor(a[x], 8);
        a[x] += __shfl_xor(a[x], 16);
        a[x] += __shfl_xor(a[x], 32);
    }
    if (q == 0) {
        float4 lo4; lo4.x = a[0]; lo4.y = a[1]; lo4.z = a[2]; lo4.w = a[3];
        float4 hi4; hi4.x = a[4]; hi4.y = a[5]; hi4.z = a[6]; hi4.w = a[7];
        *(float4*)(agg + (size_t)n * HID + c * 8) = lo4;
        *(float4*)(agg + (size_t)n * HID + c * 8 + 4) = hi4;
    }
}

// ---------------------------------------------------------------------------
// MFMA GRU: per wave 16 nodes x 384 gate outputs.
//   gates = [agg | h] @ B  (B prepped: cols 0..191 input side, 192..383 hidden)
// hi/lo bf16 split: Ah*Bh + Al*Bh + Ah*Bl (residual ~2^-18).
// Whi staged in LDS (48 KB) so the block's 4 waves read it once from L2.
__global__ __launch_bounds__(256) void k_gru(const float* __restrict__ agg,
                                             float* __restrict__ h,
                                             ushort_t* __restrict__ hb,
                                             const short* __restrict__ Whi,
                                             const short* __restrict__ Wlo,
                                             const float* __restrict__ b_ih,
                                             const float* __restrict__ b_hh) {
    __shared__ short8 sW[24 * 2 * 64];         // 48 KB
    int tid = threadIdx.x;
    {
        const short8* gW = (const short8*)Whi;
#pragma unroll
        for (int i = 0; i < 12; ++i) sW[tid + i * 256] = gW[tid + i * 256];
    }
    int wv = tid >> 6, l = tid & 63;
    int q = l >> 4, c = l & 15;
    int nodeBase = blockIdx.x * 64 + wv * 16;

    // ---- A fragments: row = lane&15, k = s*32 + q*8 + i ----
    int anode = nodeBase + c;
    int acl = (anode < N_NODES) ? anode : (N_NODES - 1);
    const float* arow = agg + (size_t)acl * HID;
    const float* hrow = h + (size_t)acl * HID;
    short8 Ag_hi[2], Ag_lo[2], Ah_hi[2], Ah_lo[2];
#pragma unroll
    for (int s = 0; s < 2; ++s) {
        int k0 = s * 32 + q * 8;
        split8(arow + k0, Ag_hi[s], Ag_lo[s]);
        split8(hrow + k0, Ah_hi[s], Ah_lo[s]);
    }
    __syncthreads();

    f32x4 acc[24];
    const f32x4 zero = {0.f, 0.f, 0.f, 0.f};
#pragma unroll
    for (int t = 0; t < 24; ++t) acc[t] = zero;

    const short8* BH = sW + l;
    const short8* BL = ((const short8*)Wlo) + l;
#pragma unroll
    for (int t = 0; t < 24; ++t) {
        short8 b0h = BH[(t * 2 + 0) * 64];
        short8 b1h = BH[(t * 2 + 1) * 64];
        short8 b0l = BL[(t * 2 + 0) * 64];
        short8 b1l = BL[(t * 2 + 1) * 64];
        short8 a0h = (t < 12) ? Ag_hi[0] : Ah_hi[0];
        short8 a0l = (t < 12) ? Ag_lo[0] : Ah_lo[0];
        short8 a1h = (t < 12) ? Ag_hi[1] : Ah_hi[1];
        short8 a1l = (t < 12) ? Ag_lo[1] : Ah_lo[1];
        acc[t] = MFMA(a0h, b0h, acc[t]);
        acc[t] = MFMA(a0l, b0h, acc[t]);
        acc[t] = MFMA(a0h, b0l, acc[t]);
        acc[t] = MFMA(a1h, b1h, acc[t]);
        acc[t] = MFMA(a1l, b1h, acc[t]);
        acc[t] = MFMA(a1h, b1l, acc[t]);
    }

    // ---- elementwise GRU, lane-local ----
    // tile t = 4g + jb covers gate g at j = jb*16 + c; node m = nodeBase + q*4 + i
#pragma unroll
    for (int jb = 0; jb < 4; ++jb) {
        int j = jb * 16 + c;
        float br  = b_ih[j] + b_hh[j];
        float bz  = b_ih[64 + j] + b_hh[64 + j];
        float bin = b_ih[128 + j];
        float bhn = b_hh[128 + j];
#pragma unroll
        for (int i = 0; i < 4; ++i) {
            int m = nodeBase + q * 4 + i;
            if (m < N_NODES) {
                float ir = acc[jb][i],      iz = acc[4 + jb][i],  inn = acc[8 + jb][i];
                float hr = acc[12 + jb][i], hz = acc[16 + jb][i], hn = acc[20 + jb][i];
                float rr = fast_sigmoid(ir + hr + br);
                float zz = fast_sigmoid(iz + hz + bz);
                float nv = fast_tanh((inn + bin) + rr * (hn + bhn));
                size_t idx = (size_t)m * HID + j;
                float hold = h[idx];
                float v = (1.0f - zz) * nv + zz * hold;
                h[idx] = v;
                hb[idx] = f2bf(v);
            }
        }
    }
}

// ---------------------------------------------------------------------------
// mean-pool from the bf16 shadow (half the read traffic of fp32 h)
#define POOL_NPW 64
__global__ void k_pool(const ushort_t* __restrict__ hb,
                       const int* __restrict__ batch,
                       float* __restrict__ sums,
                       float* __restrict__ cntf) {
    int wid = (blockIdx.x * blockDim.x + threadIdx.x) >> 6;
    int j = threadIdx.x & 63;
    int base = wid * POOL_NPW;
    if (base >= N_NODES) return;
    int end = base + POOL_NPW;
    if (end > N_NODES) end = N_NODES;
    float acc = 0.f, c = 0.f;
    int curg = batch[base];
    for (int n = base; n < end; ++n) {
        int g = batch[n];
        if (g != curg) {
            atomicAdd(&sums[(size_t)curg * HID + j], acc);
            if (j == 0) atomicAdd(&cntf[curg], c);
            acc = 0.f; c = 0.f; curg = g;
        }
        acc += __uint_as_float(((uint_t)hb[(size_t)n * HID + j]) << 16);
        c += 1.f;
    }
    atomicAdd(&sums[(size_t)curg * HID + j], acc);
    if (j == 0) atomicAdd(&cntf[curg], c);
}

__global__ void k_out(const float* __restrict__ sums,
                      const float* __restrict__ cntf,
                      const float* __restrict__ W_out,
                      const float* __restrict__ b_out,
                      float* __restrict__ out) {
    int t = blockIdx.x * blockDim.x + threadIdx.x;
    if (t >= N_GRAPHS * D_OUT) return;
    int g = t / D_OUT, o = t % D_OUT;
    float inv_c = __builtin_amdgcn_rcpf(fmaxf(cntf[g], 1.0f));
    float acc = 0.0f;
#pragma unroll
    for (int k = 0; k < HID; ++k)
        acc = fmaf(sums[g * HID + k], W_out[k * D_OUT + o], acc);
    out[t] = acc * inv_c + b_out[o];
}

// ---------------------------------------------------------------------------
static inline char* align256(char* p) {
    return (char*)(((uintptr_t)p + 255) & ~(uintptr_t)255);
}

extern "C" void kernel_launch(void* const* d_in, const int* in_sizes, int n_in,
                              void* d_out, int out_size, void* d_ws, size_t ws_size,
                              hipStream_t stream) {
    const float* node_embed = (const float*)d_in[0];
    const int*   edge_index = (const int*)  d_in[1];
    const int*   batch      = (const int*)  d_in[2];
    const float* W_in       = (const float*)d_in[3];
    const float* b_in       = (const float*)d_in[4];
    const float* ggnn_w     = (const float*)d_in[5];
    const float* gru_w_ih   = (const float*)d_in[6];
    const float* gru_w_hh   = (const float*)d_in[7];
    const float* gru_b_ih   = (const float*)d_in[8];
    const float* gru_b_hh   = (const float*)d_in[9];
    const float* W_out      = (const float*)d_in[10];
    const float* b_out      = (const float*)d_in[11];
    float* out = (float*)d_out;

    char* p = (char*)d_ws;
    float*    h     = (float*)p;    p = align256(p + (size_t)N_NODES * HID * sizeof(float));
    ushort_t* hb    = (ushort_t*)p; p = align256(p + (size_t)N_NODES * HID * sizeof(ushort_t));
    float*    agg   = (float*)p;    p = align256(p + (size_t)N_NODES * HID * sizeof(float));
    int*      csr   = (int*)p;      p = align256(p + (size_t)N_EDGES * sizeof(int));
    int*      eslot = (int*)p;      p = align256(p + (size_t)N_EDGES * sizeof(int));
    int*      off   = (int*)p;      p = align256(p + (size_t)(N_NODES + 1) * sizeof(int));
    int*      deg8  = (int*)p;      p = align256(p + (size_t)NSHARD * N_NODES * sizeof(int));
    int*      bsum  = (int*)p;      p = align256(p + 256 * sizeof(int));
    short*    Whi   = (short*)p;    p = align256(p + (size_t)N_LAYERS * WSTRIDE * sizeof(short));
    short*    Wlo   = (short*)p;    p = align256(p + (size_t)N_LAYERS * WSTRIDE * sizeof(short));
    float*    sums  = (float*)p;
    float*    cntf  = (float*)(p + (size_t)N_GRAPHS * HID * sizeof(float));

    const int BLK = 256;
    const int nchunks = (N_NODES + SCHUNK - 1) / SCHUNK;

    k_prep<<<(N_LAYERS * WSTRIDE + BLK - 1) / BLK, BLK, 0, stream>>>(
        ggnn_w, gru_w_ih, gru_w_hh, Whi, Wlo);

    hipMemsetAsync(deg8, 0, (size_t)NSHARD * N_NODES * sizeof(int), stream);
    k_hist<<<(N_EDGES + BLK - 1) / BLK, BLK, 0, stream>>>(edge_index, deg8, eslot);
    k_scan1<<<nchunks, SCHUNK, 0, stream>>>(deg8, off, bsum);
    k_scan2<<<1, 64, 0, stream>>>(bsum, off, nchunks);
    k_scan3<<<(N_NODES + BLK - 1) / BLK, BLK, 0, stream>>>(off, bsum);
    k_place<<<(N_EDGES + BLK - 1) / BLK, BLK, 0, stream>>>(edge_index, off, deg8, eslot, csr);

    k_input<<<N_NODES / LNB, BLK, 0, stream>>>(node_embed, W_in, b_in, h, hb);

    for (int l = 0; l < N_LAYERS; ++l) {
        k_gather<<<N_NODES * 64 / BLK, BLK, 0, stream>>>(off, csr, hb, agg);
        k_gru<<<(N_NODES + 63) / 64, BLK, 0, stream>>>(
            agg, h, hb, Whi + (size_t)l * WSTRIDE, Wlo + (size_t)l * WSTRIDE,
            gru_b_ih, gru_b_hh);
    }

    hipMemsetAsync(sums, 0, (size_t)N_GRAPHS * (HID + 1) * sizeof(float), stream);
    {
        int waves = (N_NODES + POOL_NPW - 1) / POOL_NPW;
        int threads = waves * 64;
        k_pool<<<(threads + BLK - 1) / BLK, BLK, 0, stream>>>(hb, batch, sums, cntf);
    }
    k_out<<<(N_GRAPHS * D_OUT + BLK - 1) / BLK, BLK, 0, stream>>>(sums, cntf, W_out, b_out, out);
}

// Round 8
// 594.697 us; speedup vs baseline: 1.0337x; 1.0337x over previous
//
#include <hip/hip_runtime.h>

#define N_NODES 100000
#define N_EDGES 1600000
#define D_IN 128
#define HID 64
#define N_LAYERS 5
#define D_OUT 32
#define N_GRAPHS 1000

#define LNB 32            // nodes per block in k_input (4 waves x 8)
#define LR 8              // nodes per thread in k_input
#define NSHARD 8          // histogram shards

typedef unsigned short ushort_t;
typedef unsigned int uint_t;
typedef __attribute__((ext_vector_type(8))) short short8;   // 8 bf16 (4 VGPRs)
typedef __attribute__((ext_vector_type(4))) float f32x4;    // MFMA accumulator

#define MFMA(a, b, c) __builtin_amdgcn_mfma_f32_16x16x32_bf16((a), (b), (c), 0, 0, 0)

// per-layer stride of the prepped weight fragment arrays (in shorts)
#define WSTRIDE (24 * 2 * 64 * 8)

__device__ __forceinline__ float fast_sigmoid(float x) {
    return __builtin_amdgcn_rcpf(1.0f + __expf(-x));
}
__device__ __forceinline__ float fast_tanh(float x) {
    return 1.0f - 2.0f * __builtin_amdgcn_rcpf(1.0f + __expf(2.0f * x));
}
// fp32 -> bf16 round-to-nearest-even
__device__ __forceinline__ ushort_t f2bf(float f) {
    uint_t u = __float_as_uint(f);
    return (ushort_t)((u + 0x7fffu + ((u >> 16) & 1u)) >> 16);
}
// load 8 consecutive floats, split each into bf16 hi + bf16 lo
__device__ __forceinline__ void split8(const float* p, short8& hi, short8& lo) {
    float4 u0 = *(const float4*)p;
    float4 u1 = *(const float4*)(p + 4);
#define SPL(ii, fv) { float f_ = (fv); ushort_t h_ = f2bf(f_); hi[ii] = (short)h_;          \
                      float r_ = f_ - __uint_as_float(((uint_t)h_) << 16); lo[ii] = (short)f2bf(r_); }
    SPL(0, u0.x) SPL(1, u0.y) SPL(2, u0.z) SPL(3, u0.w)
    SPL(4, u1.x) SPL(5, u1.y) SPL(6, u1.z) SPL(7, u1.w)
#undef SPL
}

// ---------------------------------------------------------------------------
// Weight prep (+ folded deg8 zeroing). Fragment layout:
//   idx = ((((lay*24+t)*2+s)*64+lane)*8+i, k = s*32+(lane>>4)*8+i, col = t*16+(lane&15)
//   col<192: Wc[k][col] = sum_q ggnn_w[l][k][q]*w_ih[col][q];  col>=192: w_hh[col-192][k]
__global__ void k_prep(const float* __restrict__ ggnn_w,
                       const float* __restrict__ w_ih,
                       const float* __restrict__ w_hh,
                       short* __restrict__ Whi,
                       short* __restrict__ Wlo,
                       int* __restrict__ deg8) {
    int t = blockIdx.x * blockDim.x + threadIdx.x;
    if (t < NSHARD * N_NODES) deg8[t] = 0;
    if (t >= N_LAYERS * WSTRIDE) return;
    int i    = t & 7;
    int lane = (t >> 3) & 63;
    int s    = (t >> 9) & 1;
    int tt   = (t >> 10) % 24;
    int lay  = (t >> 10) / 24;
    int k    = s * 32 + (lane >> 4) * 8 + i;
    int col  = tt * 16 + (lane & 15);
    float val;
    if (col < 192) {
        const float* wl = ggnn_w + ((size_t)lay * HID + k) * HID;
        const float* wi = w_ih + (size_t)col * HID;
        float acc = 0.0f;
#pragma unroll 8
        for (int q = 0; q < HID; ++q) acc = fmaf(wl[q], wi[q], acc);
        val = acc;
    } else {
        val = w_hh[(size_t)(col - 192) * HID + k];
    }
    ushort_t h_ = f2bf(val);
    float r_ = val - __uint_as_float(((uint_t)h_) << 16);
    Whi[t] = (short)h_;
    Wlo[t] = (short)f2bf(r_);
}

// ---------------------------------------------------------------------------
// CSR build — sharded histogram (shard = blockIdx&7)
__global__ void k_hist(const int* __restrict__ ei,
                       int* __restrict__ deg8,
                       int* __restrict__ eslot) {
    int e = blockIdx.x * blockDim.x + threadIdx.x;
    if (e >= N_EDGES) return;
    int s = blockIdx.x & (NSHARD - 1);
    eslot[e] = atomicAdd(&deg8[s * N_NODES + ei[N_EDGES + e]], 1);
}

#define SCHUNK 1024
// scan1: fold 8 shards -> total degree; convert deg8 in-place to shard-prefix.
__global__ __launch_bounds__(1024) void k_scan1(int* __restrict__ deg8,
                                                int* __restrict__ off,
                                                int* __restrict__ bsum) {
    __shared__ int buf[SCHUNK];
    int tid = threadIdx.x;
    int i = blockIdx.x * SCHUNK + tid;
    int tot = 0;
    if (i < N_NODES) {
        int pre[NSHARD];
#pragma unroll
        for (int s = 0; s < NSHARD; ++s) {
            pre[s] = tot;
            tot += deg8[s * N_NODES + i];
        }
#pragma unroll
        for (int s = 0; s < NSHARD; ++s) deg8[s * N_NODES + i] = pre[s];
    }
    buf[tid] = tot;
    __syncthreads();
    for (int s = 1; s < SCHUNK; s <<= 1) {
        int a = (tid >= s) ? buf[tid - s] : 0;
        __syncthreads();
        buf[tid] += a;
        __syncthreads();
    }
    if (i < N_NODES) off[i] = buf[tid] - tot;
    if (tid == SCHUNK - 1) bsum[blockIdx.x] = buf[tid];
}

__global__ void k_scan2(int* __restrict__ bsum, int* __restrict__ off, int nchunks) {
    if (blockIdx.x == 0 && threadIdx.x == 0) {
        int carry = 0;
        for (int b = 0; b < nchunks; ++b) {
            int t = bsum[b];
            bsum[b] = carry;
            carry += t;
        }
        off[N_NODES] = carry;
    }
}

// scan3 (+ folded sums/cnt zeroing)
__global__ void k_scan3(int* __restrict__ off, const int* __restrict__ bsum,
                        float* __restrict__ sums) {
    int i = blockIdx.x * blockDim.x + threadIdx.x;
    if (i < N_GRAPHS * (HID + 1)) sums[i] = 0.0f;
    if (i < N_NODES) off[i] += bsum[i >> 10];
}

// place: pos = off[d] + shard_prefix[s][d] + slot_within_shard
__global__ void k_place(const int* __restrict__ ei,
                        const int* __restrict__ off,
                        const int* __restrict__ deg8,
                        const int* __restrict__ eslot,
                        int* __restrict__ csr) {
    int e = blockIdx.x * blockDim.x + threadIdx.x;
    if (e >= N_EDGES) return;
    int s = blockIdx.x & (NSHARD - 1);
    int d = ei[N_EDGES + e];
    __builtin_nontemporal_store(ei[e], &csr[off[d] + deg8[s * N_NODES + d] + eslot[e]]);
}

// ---------------------------------------------------------------------------
// x = node_embed @ W_in + b_in; writes fp32 h and bf16 shadow hb
__global__ __launch_bounds__(256) void k_input(const float* __restrict__ ne,
                                               const float* __restrict__ W_in,
                                               const float* __restrict__ b_in,
                                               float* __restrict__ h,
                                               ushort_t* __restrict__ hb) {
    __shared__ float sE[LNB][D_IN];            // 16 KB
    int tid = threadIdx.x;
    int j = tid & 63, w = tid >> 6;
    int nodeBase = blockIdx.x * LNB;
    {
        const float4* g = (const float4*)(ne + (size_t)nodeBase * D_IN);
        float4* l = (float4*)&sE[0][0];
        for (int i = tid; i < LNB * D_IN / 4; i += 256) l[i] = g[i];
    }
    __syncthreads();
    float acc[LR];
#pragma unroll
    for (int r = 0; r < LR; ++r) acc[r] = 0.0f;
#pragma unroll 4
    for (int k = 0; k < D_IN; ++k) {
        float wv = W_in[k * HID + j];
#pragma unroll
        for (int r = 0; r < LR; ++r)
            acc[r] = fmaf(sE[w * LR + r][k], wv, acc[r]);
    }
    float b = b_in[j];
#pragma unroll
    for (int r = 0; r < LR; ++r) {
        int n = nodeBase + w * LR + r;
        float v = acc[r] + b;
        h[(size_t)n * HID + j] = v;
        hb[(size_t)n * HID + j] = f2bf(v);
    }
}

// ---------------------------------------------------------------------------
// CSR gather: one wave per node, 8 neighbor rows in flight (8 lanes x uint4
// = one 128B bf16 row each), 3-step shfl_xor reduce, bf16 output row.
__global__ __launch_bounds__(256) void k_gather(const int* __restrict__ off,
                                                const int* __restrict__ csr,
                                                const ushort_t* __restrict__ hb,
                                                ushort_t* __restrict__ aggb) {
    int t = blockIdx.x * blockDim.x + threadIdx.x;
    int n = t >> 6;
    int lane = t & 63;
    int q = lane >> 3, c = lane & 7;
    int beg = off[n], end = off[n + 1];
    float a[8];
#pragma unroll
    for (int x = 0; x < 8; ++x) a[x] = 0.f;
#pragma unroll 2
    for (int i = beg; i < end; i += 8) {
        int idx = i + q;
        int sidx = csr[min(idx, end - 1)];
        float msk = (idx < end) ? 1.0f : 0.0f;
        uint4 v = *(const uint4*)(hb + (size_t)sidx * HID + c * 8);
        a[0] = fmaf(msk, __uint_as_float(v.x << 16), a[0]);
        a[1] = fmaf(msk, __uint_as_float(v.x & 0xffff0000u), a[1]);
        a[2] = fmaf(msk, __uint_as_float(v.y << 16), a[2]);
        a[3] = fmaf(msk, __uint_as_float(v.y & 0xffff0000u), a[3]);
        a[4] = fmaf(msk, __uint_as_float(v.z << 16), a[4]);
        a[5] = fmaf(msk, __uint_as_float(v.z & 0xffff0000u), a[5]);
        a[6] = fmaf(msk, __uint_as_float(v.w << 16), a[6]);
        a[7] = fmaf(msk, __uint_as_float(v.w & 0xffff0000u), a[7]);
    }
#pragma unroll
    for (int x = 0; x < 8; ++x) {
        a[x] += __shfl_xor(a[x], 8);
        a[x] += __shfl_xor(a[x], 16);
        a[x] += __shfl_xor(a[x], 32);
    }
    if (q == 0) {
        uint4 o;
        o.x = (uint_t)f2bf(a[0]) | ((uint_t)f2bf(a[1]) << 16);
        o.y = (uint_t)f2bf(a[2]) | ((uint_t)f2bf(a[3]) << 16);
        o.z = (uint_t)f2bf(a[4]) | ((uint_t)f2bf(a[5]) << 16);
        o.w = (uint_t)f2bf(a[6]) | ((uint_t)f2bf(a[7]) << 16);
        *(uint4*)(aggb + (size_t)n * HID + c * 8) = o;
    }
}

// ---------------------------------------------------------------------------
// MFMA GRU: per wave 16 nodes x 384 gate outputs.
// Input side A (aggb) is bf16 already -> direct frag, 2 MFMAs per k-half.
// Hidden side A (h fp32) uses hi/lo split -> 3 MFMAs per k-half.
// Whi staged in LDS (48 KB).
__global__ __launch_bounds__(256) void k_gru(const ushort_t* __restrict__ aggb,
                                             float* __restrict__ h,
                                             ushort_t* __restrict__ hb,
                                             const short* __restrict__ Whi,
                                             const short* __restrict__ Wlo,
                                             const float* __restrict__ b_ih,
                                             const float* __restrict__ b_hh) {
    __shared__ short8 sW[24 * 2 * 64];         // 48 KB
    int tid = threadIdx.x;
    {
        const short8* gW = (const short8*)Whi;
#pragma unroll
        for (int i = 0; i < 12; ++i) sW[tid + i * 256] = gW[tid + i * 256];
    }
    int wv = tid >> 6, l = tid & 63;
    int q = l >> 4, c = l & 15;
    int nodeBase = blockIdx.x * 64 + wv * 16;

    // ---- A fragments: row = lane&15, k = s*32 + q*8 + i ----
    int anode = nodeBase + c;
    int acl = (anode < N_NODES) ? anode : (N_NODES - 1);
    const ushort_t* arow = aggb + (size_t)acl * HID;
    const float* hrow = h + (size_t)acl * HID;
    short8 Ag[2], Ah_hi[2], Ah_lo[2];
    Ag[0] = *(const short8*)(arow + q * 8);
    Ag[1] = *(const short8*)(arow + 32 + q * 8);
#pragma unroll
    for (int s = 0; s < 2; ++s)
        split8(hrow + s * 32 + q * 8, Ah_hi[s], Ah_lo[s]);
    __syncthreads();

    f32x4 acc[24];
    const f32x4 zero = {0.f, 0.f, 0.f, 0.f};
#pragma unroll
    for (int t = 0; t < 24; ++t) acc[t] = zero;

    const short8* BH = sW + l;
    const short8* BL = ((const short8*)Wlo) + l;
#pragma unroll
    for (int t = 0; t < 24; ++t) {
        short8 b0h = BH[(t * 2 + 0) * 64];
        short8 b1h = BH[(t * 2 + 1) * 64];
        short8 b0l = BL[(t * 2 + 0) * 64];
        short8 b1l = BL[(t * 2 + 1) * 64];
        if (t < 12) {
            acc[t] = MFMA(Ag[0], b0h, acc[t]);
            acc[t] = MFMA(Ag[0], b0l, acc[t]);
            acc[t] = MFMA(Ag[1], b1h, acc[t]);
            acc[t] = MFMA(Ag[1], b1l, acc[t]);
        } else {
            acc[t] = MFMA(Ah_hi[0], b0h, acc[t]);
            acc[t] = MFMA(Ah_lo[0], b0h, acc[t]);
            acc[t] = MFMA(Ah_hi[0], b0l, acc[t]);
            acc[t] = MFMA(Ah_hi[1], b1h, acc[t]);
            acc[t] = MFMA(Ah_lo[1], b1h, acc[t]);
            acc[t] = MFMA(Ah_hi[1], b1l, acc[t]);
        }
    }

    // ---- elementwise GRU, lane-local ----
#pragma unroll
    for (int jb = 0; jb < 4; ++jb) {
        int j = jb * 16 + c;
        float br  = b_ih[j] + b_hh[j];
        float bz  = b_ih[64 + j] + b_hh[64 + j];
        float bin = b_ih[128 + j];
        float bhn = b_hh[128 + j];
#pragma unroll
        for (int i = 0; i < 4; ++i) {
            int m = nodeBase + q * 4 + i;
            if (m < N_NODES) {
                float ir = acc[jb][i],      iz = acc[4 + jb][i],  inn = acc[8 + jb][i];
                float hr = acc[12 + jb][i], hz = acc[16 + jb][i], hn = acc[20 + jb][i];
                float rr = fast_sigmoid(ir + hr + br);
                float zz = fast_sigmoid(iz + hz + bz);
                float nv = fast_tanh((inn + bin) + rr * (hn + bhn));
                size_t idx = (size_t)m * HID + j;
                float hold = h[idx];
                float v = (1.0f - zz) * nv + zz * hold;
                h[idx] = v;
                hb[idx] = f2bf(v);
            }
        }
    }
}

// ---------------------------------------------------------------------------
// mean-pool from the bf16 shadow
#define POOL_NPW 64
__global__ void k_pool(const ushort_t* __restrict__ hb,
                       const int* __restrict__ batch,
                       float* __restrict__ sums,
                       float* __restrict__ cntf) {
    int wid = (blockIdx.x * blockDim.x + threadIdx.x) >> 6;
    int j = threadIdx.x & 63;
    int base = wid * POOL_NPW;
    if (base >= N_NODES) return;
    int end = base + POOL_NPW;
    if (end > N_NODES) end = N_NODES;
    float acc = 0.f, c = 0.f;
    int curg = batch[base];
    for (int n = base; n < end; ++n) {
        int g = batch[n];
        if (g != curg) {
            atomicAdd(&sums[(size_t)curg * HID + j], acc);
            if (j == 0) atomicAdd(&cntf[curg], c);
            acc = 0.f; c = 0.f; curg = g;
        }
        acc += __uint_as_float(((uint_t)hb[(size_t)n * HID + j]) << 16);
        c += 1.f;
    }
    atomicAdd(&sums[(size_t)curg * HID + j], acc);
    if (j == 0) atomicAdd(&cntf[curg], c);
}

__global__ void k_out(const float* __restrict__ sums,
                      const float* __restrict__ cntf,
                      const float* __restrict__ W_out,
                      const float* __restrict__ b_out,
                      float* __restrict__ out) {
    int t = blockIdx.x * blockDim.x + threadIdx.x;
    if (t >= N_GRAPHS * D_OUT) return;
    int g = t / D_OUT, o = t % D_OUT;
    float inv_c = __builtin_amdgcn_rcpf(fmaxf(cntf[g], 1.0f));
    float acc = 0.0f;
#pragma unroll
    for (int k = 0; k < HID; ++k)
        acc = fmaf(sums[g * HID + k], W_out[k * D_OUT + o], acc);
    out[t] = acc * inv_c + b_out[o];
}

// ---------------------------------------------------------------------------
static inline char* align256(char* p) {
    return (char*)(((uintptr_t)p + 255) & ~(uintptr_t)255);
}

extern "C" void kernel_launch(void* const* d_in, const int* in_sizes, int n_in,
                              void* d_out, int out_size, void* d_ws, size_t ws_size,
                              hipStream_t stream) {
    const float* node_embed = (const float*)d_in[0];
    const int*   edge_index = (const int*)  d_in[1];
    const int*   batch      = (const int*)  d_in[2];
    const float* W_in       = (const float*)d_in[3];
    const float* b_in       = (const float*)d_in[4];
    const float* ggnn_w     = (const float*)d_in[5];
    const float* gru_w_ih   = (const float*)d_in[6];
    const float* gru_w_hh   = (const float*)d_in[7];
    const float* gru_b_ih   = (const float*)d_in[8];
    const float* gru_b_hh   = (const float*)d_in[9];
    const float* W_out      = (const float*)d_in[10];
    const float* b_out      = (const float*)d_in[11];
    float* out = (float*)d_out;

    char* p = (char*)d_ws;
    float*    h     = (float*)p;    p = align256(p + (size_t)N_NODES * HID * sizeof(float));
    ushort_t* hb    = (ushort_t*)p; p = align256(p + (size_t)N_NODES * HID * sizeof(ushort_t));
    ushort_t* aggb  = (ushort_t*)p; p = align256(p + (size_t)N_NODES * HID * sizeof(ushort_t));
    int*      csr   = (int*)p;      p = align256(p + (size_t)N_EDGES * sizeof(int));
    int*      eslot = (int*)p;      p = align256(p + (size_t)N_EDGES * sizeof(int));
    int*      off   = (int*)p;      p = align256(p + (size_t)(N_NODES + 1) * sizeof(int));
    int*      deg8  = (int*)p;      p = align256(p + (size_t)NSHARD * N_NODES * sizeof(int));
    int*      bsum  = (int*)p;      p = align256(p + 256 * sizeof(int));
    short*    Whi   = (short*)p;    p = align256(p + (size_t)N_LAYERS * WSTRIDE * sizeof(short));
    short*    Wlo   = (short*)p;    p = align256(p + (size_t)N_LAYERS * WSTRIDE * sizeof(short));
    float*    sums  = (float*)p;
    float*    cntf  = (float*)(p + (size_t)N_GRAPHS * HID * sizeof(float));

    const int BLK = 256;
    const int nchunks = (N_NODES + SCHUNK - 1) / SCHUNK;

    // weight prep + deg8 zeroing (folded)
    k_prep<<<(NSHARD * N_NODES + BLK - 1) / BLK, BLK, 0, stream>>>(
        ggnn_w, gru_w_ih, gru_w_hh, Whi, Wlo, deg8);

    k_hist<<<(N_EDGES + BLK - 1) / BLK, BLK, 0, stream>>>(edge_index, deg8, eslot);
    k_scan1<<<nchunks, SCHUNK, 0, stream>>>(deg8, off, bsum);
    k_scan2<<<1, 64, 0, stream>>>(bsum, off, nchunks);
    k_scan3<<<(N_NODES + BLK - 1) / BLK, BLK, 0, stream>>>(off, bsum, sums);
    k_place<<<(N_EDGES + BLK - 1) / BLK, BLK, 0, stream>>>(edge_index, off, deg8, eslot, csr);

    k_input<<<N_NODES / LNB, BLK, 0, stream>>>(node_embed, W_in, b_in, h, hb);

    for (int l = 0; l < N_LAYERS; ++l) {
        k_gather<<<N_NODES * 64 / BLK, BLK, 0, stream>>>(off, csr, hb, aggb);
        k_gru<<<(N_NODES + 63) / 64, BLK, 0, stream>>>(
            aggb, h, hb, Whi + (size_t)l * WSTRIDE, Wlo + (size_t)l * WSTRIDE,
            gru_b_ih, gru_b_hh);
    }

    {
        int waves = (N_NODES + POOL_NPW - 1) / POOL_NPW;
        int threads = waves * 64;
        k_pool<<<(threads + BLK - 1) / BLK, BLK, 0, stream>>>(hb, batch, sums, cntf);
    }
    k_out<<<(N_GRAPHS * D_OUT + BLK - 1) / BLK, BLK, 0, stream>>>(sums, cntf, W_out, b_out, out);
}

// Round 9
// 564.380 us; speedup vs baseline: 1.0892x; 1.0537x over previous
//
#include <hip/hip_runtime.h>

#define N_NODES 100000
#define N_EDGES 1600000
#define D_IN 128
#define HID 64
#define N_LAYERS 5
#define D_OUT 32
#define N_GRAPHS 1000

#define LNB 32            // nodes per input-block (4 waves x 8)
#define LR 8              // nodes per thread in input

typedef unsigned short ushort_t;
typedef unsigned int uint_t;
typedef __attribute__((ext_vector_type(8))) short short8;   // 8 bf16 (4 VGPRs)
typedef __attribute__((ext_vector_type(4))) float f32x4;    // MFMA accumulator

#define MFMA(a, b, c) __builtin_amdgcn_mfma_f32_16x16x32_bf16((a), (b), (c), 0, 0, 0)

// per-layer stride of the prepped weight fragment arrays (in shorts)
#define WSTRIDE (24 * 2 * 64 * 8)

// k_front block-range split
#define HIST_B  (N_EDGES / 256)                  // 6250
#define INPUT_B (N_NODES / LNB)                  // 3125
#define PREP_B  ((N_LAYERS * WSTRIDE + 255) / 256)  // 480

__device__ __forceinline__ float fast_sigmoid(float x) {
    return __builtin_amdgcn_rcpf(1.0f + __expf(-x));
}
__device__ __forceinline__ float fast_tanh(float x) {
    return 1.0f - 2.0f * __builtin_amdgcn_rcpf(1.0f + __expf(2.0f * x));
}
// fp32 -> bf16 round-to-nearest-even
__device__ __forceinline__ ushort_t f2bf(float f) {
    uint_t u = __float_as_uint(f);
    return (ushort_t)((u + 0x7fffu + ((u >> 16) & 1u)) >> 16);
}
__device__ __forceinline__ float b2f(ushort_t u) {
    return __uint_as_float(((uint_t)u) << 16);
}

// ---------------------------------------------------------------------------
// Fused front-end: [0,HIST_B) histogram | [HIST_B,+INPUT_B) input linear |
// [.., +PREP_B) weight prep. All three are mutually independent; hist is
// atomic-latency-bound (VALUBusy ~0.7%) so the other two hide inside it.
__global__ __launch_bounds__(256) void k_front(
        const int* __restrict__ ei,
        int* __restrict__ deg, int* __restrict__ eslot,
        const float* __restrict__ ne, const float* __restrict__ W_in,
        const float* __restrict__ b_in,
        ushort_t* __restrict__ hbhi, ushort_t* __restrict__ hblo,
        const float* __restrict__ ggnn_w, const float* __restrict__ w_ih,
        const float* __restrict__ w_hh,
        short* __restrict__ Whi, short* __restrict__ Wlo) {
    __shared__ float sE[LNB][D_IN];            // 16 KB (input path only)
    int b = blockIdx.x;
    int tid = threadIdx.x;

    if (b < HIST_B) {
        // ---- histogram ----
        int e = b * 256 + tid;
        eslot[e] = atomicAdd(&deg[ei[N_EDGES + e]], 1);
        return;
    }
    if (b < HIST_B + INPUT_B) {
        // ---- input linear: x = ne @ W_in + b_in ----
        int j = tid & 63, w = tid >> 6;
        int nodeBase = (b - HIST_B) * LNB;
        {
            const float4* g = (const float4*)(ne + (size_t)nodeBase * D_IN);
            float4* l = (float4*)&sE[0][0];
            for (int i = tid; i < LNB * D_IN / 4; i += 256) l[i] = g[i];
        }
        __syncthreads();
        float acc[LR];
#pragma unroll
        for (int r = 0; r < LR; ++r) acc[r] = 0.0f;
#pragma unroll 4
        for (int k = 0; k < D_IN; ++k) {
            float wv = W_in[k * HID + j];
#pragma unroll
            for (int r = 0; r < LR; ++r)
                acc[r] = fmaf(sE[w * LR + r][k], wv, acc[r]);
        }
        float bb = b_in[j];
#pragma unroll
        for (int r = 0; r < LR; ++r) {
            int n = nodeBase + w * LR + r;
            float v = acc[r] + bb;
            ushort_t hi = f2bf(v);
            size_t idx = (size_t)n * HID + j;
            hbhi[idx] = hi;
            hblo[idx] = f2bf(v - b2f(hi));
        }
        return;
    }
    // ---- weight prep ----
    // idx = ((((lay*24+t)*2+s)*64+lane)*8+i, k = s*32+(lane>>4)*8+i, col = t*16+(lane&15)
    // col<192: Wc[k][col] = sum_q ggnn_w[l][k][q]*w_ih[col][q]; col>=192: w_hh[col-192][k]
    int t = (b - HIST_B - INPUT_B) * 256 + tid;
    if (t >= N_LAYERS * WSTRIDE) return;
    int i    = t & 7;
    int lane = (t >> 3) & 63;
    int s    = (t >> 9) & 1;
    int tt   = (t >> 10) % 24;
    int lay  = (t >> 10) / 24;
    int k    = s * 32 + (lane >> 4) * 8 + i;
    int col  = tt * 16 + (lane & 15);
    float val;
    if (col < 192) {
        const float* wl = ggnn_w + ((size_t)lay * HID + k) * HID;
        const float* wi = w_ih + (size_t)col * HID;
        float acc = 0.0f;
#pragma unroll 8
        for (int q = 0; q < HID; ++q) acc = fmaf(wl[q], wi[q], acc);
        val = acc;
    } else {
        val = w_hh[(size_t)(col - 192) * HID + k];
    }
    ushort_t h_ = f2bf(val);
    Whi[t] = (short)h_;
    Wlo[t] = (short)f2bf(val - b2f(h_));
}

// ---------------------------------------------------------------------------
#define SCHUNK 1024
__global__ __launch_bounds__(1024) void k_scan1(const int* __restrict__ deg,
                                                int* __restrict__ off,
                                                int* __restrict__ bsum) {
    __shared__ int buf[SCHUNK];
    int tid = threadIdx.x;
    int i = blockIdx.x * SCHUNK + tid;
    int v = (i < N_NODES) ? deg[i] : 0;
    buf[tid] = v;
    __syncthreads();
    for (int s = 1; s < SCHUNK; s <<= 1) {
        int a = (tid >= s) ? buf[tid - s] : 0;
        __syncthreads();
        buf[tid] += a;
        __syncthreads();
    }
    if (i < N_NODES) off[i] = buf[tid] - v;
    if (tid == SCHUNK - 1) bsum[blockIdx.x] = buf[tid];
}

__global__ void k_scan2(int* __restrict__ bsum, int* __restrict__ off, int nchunks) {
    if (blockIdx.x == 0 && threadIdx.x == 0) {
        int carry = 0;
        for (int b = 0; b < nchunks; ++b) {
            int t = bsum[b];
            bsum[b] = carry;
            carry += t;
        }
        off[N_NODES] = carry;
    }
}

// scan3 (+ folded sums/cnt zeroing)
__global__ void k_scan3(int* __restrict__ off, const int* __restrict__ bsum,
                        float* __restrict__ sums) {
    int i = blockIdx.x * blockDim.x + threadIdx.x;
    if (i < N_GRAPHS * (HID + 1)) sums[i] = 0.0f;
    if (i < N_NODES) off[i] += bsum[i >> 10];
}

// place: pos = off[d] + eslot[e]
__global__ void k_place(const int* __restrict__ ei,
                        const int* __restrict__ off,
                        const int* __restrict__ eslot,
                        int* __restrict__ csr) {
    int e = blockIdx.x * blockDim.x + threadIdx.x;
    if (e >= N_EDGES) return;
    int d = ei[N_EDGES + e];
    __builtin_nontemporal_store(ei[e], &csr[off[d] + eslot[e]]);
}

// ---------------------------------------------------------------------------
// CSR gather: one wave per node, 8 neighbor rows in flight (8 lanes x uint4
// = one 128B bf16 row each), 3-step shfl_xor reduce, bf16 output row.
__global__ __launch_bounds__(256) void k_gather(const int* __restrict__ off,
                                                const int* __restrict__ csr,
                                                const ushort_t* __restrict__ hb,
                                                ushort_t* __restrict__ aggb) {
    int t = blockIdx.x * blockDim.x + threadIdx.x;
    int n = t >> 6;
    int lane = t & 63;
    int q = lane >> 3, c = lane & 7;
    int beg = off[n], end = off[n + 1];
    float a[8];
#pragma unroll
    for (int x = 0; x < 8; ++x) a[x] = 0.f;
#pragma unroll 2
    for (int i = beg; i < end; i += 8) {
        int idx = i + q;
        int sidx = csr[min(idx, end - 1)];
        float msk = (idx < end) ? 1.0f : 0.0f;
        uint4 v = *(const uint4*)(hb + (size_t)sidx * HID + c * 8);
        a[0] = fmaf(msk, __uint_as_float(v.x << 16), a[0]);
        a[1] = fmaf(msk, __uint_as_float(v.x & 0xffff0000u), a[1]);
        a[2] = fmaf(msk, __uint_as_float(v.y << 16), a[2]);
        a[3] = fmaf(msk, __uint_as_float(v.y & 0xffff0000u), a[3]);
        a[4] = fmaf(msk, __uint_as_float(v.z << 16), a[4]);
        a[5] = fmaf(msk, __uint_as_float(v.z & 0xffff0000u), a[5]);
        a[6] = fmaf(msk, __uint_as_float(v.w << 16), a[6]);
        a[7] = fmaf(msk, __uint_as_float(v.w & 0xffff0000u), a[7]);
    }
#pragma unroll
    for (int x = 0; x < 8; ++x) {
        a[x] += __shfl_xor(a[x], 8);
        a[x] += __shfl_xor(a[x], 16);
        a[x] += __shfl_xor(a[x], 32);
    }
    if (q == 0) {
        uint4 o;
        o.x = (uint_t)f2bf(a[0]) | ((uint_t)f2bf(a[1]) << 16);
        o.y = (uint_t)f2bf(a[2]) | ((uint_t)f2bf(a[3]) << 16);
        o.z = (uint_t)f2bf(a[4]) | ((uint_t)f2bf(a[5]) << 16);
        o.w = (uint_t)f2bf(a[6]) | ((uint_t)f2bf(a[7]) << 16);
        *(uint4*)(aggb + (size_t)n * HID + c * 8) = o;
    }
}

// ---------------------------------------------------------------------------
// MFMA GRU. State h is stored as two bf16 planes (hi + lo residual ~ fp21):
// hidden-side A fragments are direct short8 loads (no split VALU), and hold
// is reconstructed hi+lo. Input side A (aggb) is plain bf16.
// Whi staged in LDS (48 KB).
__global__ __launch_bounds__(256) void k_gru(const ushort_t* __restrict__ aggb,
                                             ushort_t* __restrict__ hbhi,
                                             ushort_t* __restrict__ hblo,
                                             const short* __restrict__ Whi,
                                             const short* __restrict__ Wlo,
                                             const float* __restrict__ b_ih,
                                             const float* __restrict__ b_hh) {
    __shared__ short8 sW[24 * 2 * 64];         // 48 KB
    int tid = threadIdx.x;
    {
        const short8* gW = (const short8*)Whi;
#pragma unroll
        for (int i = 0; i < 12; ++i) sW[tid + i * 256] = gW[tid + i * 256];
    }
    int wv = tid >> 6, l = tid & 63;
    int q = l >> 4, c = l & 15;
    int nodeBase = blockIdx.x * 64 + wv * 16;

    // ---- A fragments: row = lane&15, k = s*32 + q*8 + i ----
    int anode = nodeBase + c;
    int acl = (anode < N_NODES) ? anode : (N_NODES - 1);
    const ushort_t* arow = aggb + (size_t)acl * HID;
    const ushort_t* hrowh = hbhi + (size_t)acl * HID;
    const ushort_t* hrowl = hblo + (size_t)acl * HID;
    short8 Ag[2], Ah_hi[2], Ah_lo[2];
    Ag[0] = *(const short8*)(arow + q * 8);
    Ag[1] = *(const short8*)(arow + 32 + q * 8);
    Ah_hi[0] = *(const short8*)(hrowh + q * 8);
    Ah_hi[1] = *(const short8*)(hrowh + 32 + q * 8);
    Ah_lo[0] = *(const short8*)(hrowl + q * 8);
    Ah_lo[1] = *(const short8*)(hrowl + 32 + q * 8);
    __syncthreads();

    f32x4 acc[24];
    const f32x4 zero = {0.f, 0.f, 0.f, 0.f};
#pragma unroll
    for (int t = 0; t < 24; ++t) acc[t] = zero;

    const short8* BH = sW + l;
    const short8* BL = ((const short8*)Wlo) + l;
#pragma unroll
    for (int t = 0; t < 24; ++t) {
        short8 b0h = BH[(t * 2 + 0) * 64];
        short8 b1h = BH[(t * 2 + 1) * 64];
        short8 b0l = BL[(t * 2 + 0) * 64];
        short8 b1l = BL[(t * 2 + 1) * 64];
        if (t < 12) {
            acc[t] = MFMA(Ag[0], b0h, acc[t]);
            acc[t] = MFMA(Ag[0], b0l, acc[t]);
            acc[t] = MFMA(Ag[1], b1h, acc[t]);
            acc[t] = MFMA(Ag[1], b1l, acc[t]);
        } else {
            acc[t] = MFMA(Ah_hi[0], b0h, acc[t]);
            acc[t] = MFMA(Ah_lo[0], b0h, acc[t]);
            acc[t] = MFMA(Ah_hi[0], b0l, acc[t]);
            acc[t] = MFMA(Ah_hi[1], b1h, acc[t]);
            acc[t] = MFMA(Ah_lo[1], b1h, acc[t]);
            acc[t] = MFMA(Ah_hi[1], b1l, acc[t]);
        }
    }

    // ---- elementwise GRU, lane-local ----
#pragma unroll
    for (int jb = 0; jb < 4; ++jb) {
        int j = jb * 16 + c;
        float br  = b_ih[j] + b_hh[j];
        float bz  = b_ih[64 + j] + b_hh[64 + j];
        float bin = b_ih[128 + j];
        float bhn = b_hh[128 + j];
#pragma unroll
        for (int i = 0; i < 4; ++i) {
            int m = nodeBase + q * 4 + i;
            if (m < N_NODES) {
                float ir = acc[jb][i],      iz = acc[4 + jb][i],  inn = acc[8 + jb][i];
                float hr = acc[12 + jb][i], hz = acc[16 + jb][i], hn = acc[20 + jb][i];
                float rr = fast_sigmoid(ir + hr + br);
                float zz = fast_sigmoid(iz + hz + bz);
                float nv = fast_tanh((inn + bin) + rr * (hn + bhn));
                size_t idx = (size_t)m * HID + j;
                float hold = b2f(hbhi[idx]) + b2f(hblo[idx]);
                float v = (1.0f - zz) * nv + zz * hold;
                ushort_t hi = f2bf(v);
                hbhi[idx] = hi;
                hblo[idx] = f2bf(v - b2f(hi));
            }
        }
    }
}

// ---------------------------------------------------------------------------
// mean-pool from the bf16 hi plane
#define POOL_NPW 32
__global__ void k_pool(const ushort_t* __restrict__ hb,
                       const int* __restrict__ batch,
                       float* __restrict__ sums,
                       float* __restrict__ cntf) {
    int wid = (blockIdx.x * blockDim.x + threadIdx.x) >> 6;
    int j = threadIdx.x & 63;
    int base = wid * POOL_NPW;
    if (base >= N_NODES) return;
    int end = base + POOL_NPW;
    if (end > N_NODES) end = N_NODES;
    float acc = 0.f, c = 0.f;
    int curg = batch[base];
    for (int n = base; n < end; ++n) {
        int g = batch[n];
        if (g != curg) {
            atomicAdd(&sums[(size_t)curg * HID + j], acc);
            if (j == 0) atomicAdd(&cntf[curg], c);
            acc = 0.f; c = 0.f; curg = g;
        }
        acc += b2f(hb[(size_t)n * HID + j]);
        c += 1.f;
    }
    atomicAdd(&sums[(size_t)curg * HID + j], acc);
    if (j == 0) atomicAdd(&cntf[curg], c);
}

__global__ void k_out(const float* __restrict__ sums,
                      const float* __restrict__ cntf,
                      const float* __restrict__ W_out,
                      const float* __restrict__ b_out,
                      float* __restrict__ out) {
    int t = blockIdx.x * blockDim.x + threadIdx.x;
    if (t >= N_GRAPHS * D_OUT) return;
    int g = t / D_OUT, o = t % D_OUT;
    float inv_c = __builtin_amdgcn_rcpf(fmaxf(cntf[g], 1.0f));
    float acc = 0.0f;
#pragma unroll
    for (int k = 0; k < HID; ++k)
        acc = fmaf(sums[g * HID + k], W_out[k * D_OUT + o], acc);
    out[t] = acc * inv_c + b_out[o];
}

// ---------------------------------------------------------------------------
static inline char* align256(char* p) {
    return (char*)(((uintptr_t)p + 255) & ~(uintptr_t)255);
}

extern "C" void kernel_launch(void* const* d_in, const int* in_sizes, int n_in,
                              void* d_out, int out_size, void* d_ws, size_t ws_size,
                              hipStream_t stream) {
    const float* node_embed = (const float*)d_in[0];
    const int*   edge_index = (const int*)  d_in[1];
    const int*   batch      = (const int*)  d_in[2];
    const float* W_in       = (const float*)d_in[3];
    const float* b_in       = (const float*)d_in[4];
    const float* ggnn_w     = (const float*)d_in[5];
    const float* gru_w_ih   = (const float*)d_in[6];
    const float* gru_w_hh   = (const float*)d_in[7];
    const float* gru_b_ih   = (const float*)d_in[8];
    const float* gru_b_hh   = (const float*)d_in[9];
    const float* W_out      = (const float*)d_in[10];
    const float* b_out      = (const float*)d_in[11];
    float* out = (float*)d_out;

    char* p = (char*)d_ws;
    ushort_t* hbhi  = (ushort_t*)p; p = align256(p + (size_t)N_NODES * HID * sizeof(ushort_t));
    ushort_t* hblo  = (ushort_t*)p; p = align256(p + (size_t)N_NODES * HID * sizeof(ushort_t));
    ushort_t* aggb  = (ushort_t*)p; p = align256(p + (size_t)N_NODES * HID * sizeof(ushort_t));
    int*      csr   = (int*)p;      p = align256(p + (size_t)N_EDGES * sizeof(int));
    int*      eslot = (int*)p;      p = align256(p + (size_t)N_EDGES * sizeof(int));
    int*      off   = (int*)p;      p = align256(p + (size_t)(N_NODES + 1) * sizeof(int));
    int*      deg   = (int*)p;      p = align256(p + (size_t)N_NODES * sizeof(int));
    int*      bsum  = (int*)p;      p = align256(p + 256 * sizeof(int));
    short*    Whi   = (short*)p;    p = align256(p + (size_t)N_LAYERS * WSTRIDE * sizeof(short));
    short*    Wlo   = (short*)p;    p = align256(p + (size_t)N_LAYERS * WSTRIDE * sizeof(short));
    float*    sums  = (float*)p;
    float*    cntf  = (float*)(p + (size_t)N_GRAPHS * HID * sizeof(float));

    const int BLK = 256;
    const int nchunks = (N_NODES + SCHUNK - 1) / SCHUNK;

    hipMemsetAsync(deg, 0, (size_t)N_NODES * sizeof(int), stream);

    // fused: histogram | input linear | weight prep
    k_front<<<HIST_B + INPUT_B + PREP_B, BLK, 0, stream>>>(
        edge_index, deg, eslot,
        node_embed, W_in, b_in, hbhi, hblo,
        ggnn_w, gru_w_ih, gru_w_hh, Whi, Wlo);

    k_scan1<<<nchunks, SCHUNK, 0, stream>>>(deg, off, bsum);
    k_scan2<<<1, 64, 0, stream>>>(bsum, off, nchunks);
    k_scan3<<<(N_NODES + BLK - 1) / BLK, BLK, 0, stream>>>(off, bsum, sums);
    k_place<<<(N_EDGES + BLK - 1) / BLK, BLK, 0, stream>>>(edge_index, off, eslot, csr);

    for (int l = 0; l < N_LAYERS; ++l) {
        k_gather<<<N_NODES * 64 / BLK, BLK, 0, stream>>>(off, csr, hbhi, aggb);
        k_gru<<<(N_NODES + 63) / 64, BLK, 0, stream>>>(
            aggb, hbhi, hblo, Whi + (size_t)l * WSTRIDE, Wlo + (size_t)l * WSTRIDE,
            gru_b_ih, gru_b_hh);
    }

    {
        int waves = (N_NODES + POOL_NPW - 1) / POOL_NPW;
        int threads = waves * 64;
        k_pool<<<(threads + BLK - 1) / BLK, BLK, 0, stream>>>(hbhi, batch, sums, cntf);
    }
    k_out<<<(N_GRAPHS * D_OUT + BLK - 1) / BLK, BLK, 0, stream>>>(sums, cntf, W_out, b_out, out);
}

// Round 10
// 547.204 us; speedup vs baseline: 1.1234x; 1.0314x over previous
//
#include <hip/hip_runtime.h>

#define N_NODES 100000
#define N_EDGES 1600000
#define D_IN 128
#define HID 64
#define N_LAYERS 5
#define D_OUT 32
#define N_GRAPHS 1000

#define LNB 32            // nodes per input-block (4 waves x 8)
#define LR 8              // nodes per thread in input

typedef unsigned short ushort_t;
typedef unsigned int uint_t;
typedef __attribute__((ext_vector_type(8))) short short8;   // 8 bf16 (4 VGPRs)
typedef __attribute__((ext_vector_type(4))) float f32x4;    // MFMA accumulator

#define MFMA(a, b, c) __builtin_amdgcn_mfma_f32_16x16x32_bf16((a), (b), (c), 0, 0, 0)

// per-layer stride of the prepped weight fragment arrays (in shorts)
#define WSTRIDE (24 * 2 * 64 * 8)

#define HIST_B  (N_EDGES / 256)                     // 6250
#define INPUT_B (N_NODES / LNB)                     // 3125
#define PREP_B  ((N_LAYERS * WSTRIDE + 255) / 256)  // 480
#define PLACE_B (N_EDGES / 256)                     // 6250

__device__ __forceinline__ float fast_sigmoid(float x) {
    return __builtin_amdgcn_rcpf(1.0f + __expf(-x));
}
__device__ __forceinline__ float fast_tanh(float x) {
    return 1.0f - 2.0f * __builtin_amdgcn_rcpf(1.0f + __expf(2.0f * x));
}
// fp32 -> bf16 round-to-nearest-even
__device__ __forceinline__ ushort_t f2bf(float f) {
    uint_t u = __float_as_uint(f);
    return (ushort_t)((u + 0x7fffu + ((u >> 16) & 1u)) >> 16);
}
__device__ __forceinline__ float b2f(ushort_t u) {
    return __uint_as_float(((uint_t)u) << 16);
}

// ---------------------------------------------------------------------------
// Front: histogram + weight-prep, role-INTERLEAVED (prep every 14th block) so
// both are co-resident — prep's VALU hides inside hist's atomic latency.
__global__ __launch_bounds__(256) void k_front(
        const int* __restrict__ ei,
        int* __restrict__ deg, int* __restrict__ eslot,
        const float* __restrict__ ggnn_w, const float* __restrict__ w_ih,
        const float* __restrict__ w_hh,
        short* __restrict__ Whi, short* __restrict__ Wlo) {
    int b = blockIdx.x;
    int tid = threadIdx.x;

    if ((b % 14) == 0 && (b / 14) < PREP_B) {
        // ---- weight prep ----
        int t = (b / 14) * 256 + tid;
        if (t >= N_LAYERS * WSTRIDE) return;
        int i    = t & 7;
        int lane = (t >> 3) & 63;
        int s    = (t >> 9) & 1;
        int tt   = (t >> 10) % 24;
        int lay  = (t >> 10) / 24;
        int k    = s * 32 + (lane >> 4) * 8 + i;
        int col  = tt * 16 + (lane & 15);
        float val;
        if (col < 192) {
            const float* wl = ggnn_w + ((size_t)lay * HID + k) * HID;
            const float* wi = w_ih + (size_t)col * HID;
            float acc = 0.0f;
#pragma unroll 8
            for (int q = 0; q < HID; ++q) acc = fmaf(wl[q], wi[q], acc);
            val = acc;
        } else {
            val = w_hh[(size_t)(col - 192) * HID + k];
        }
        ushort_t h_ = f2bf(val);
        Whi[t] = (short)h_;
        Wlo[t] = (short)f2bf(val - b2f(h_));
        return;
    }
    // ---- histogram ----
    int hb_idx = b - min((b + 13) / 14, PREP_B);
    int e = hb_idx * 256 + tid;
    eslot[e] = atomicAdd(&deg[ei[N_EDGES + e]], 1);
}

// ---------------------------------------------------------------------------
#define SCHUNK 1024
__global__ __launch_bounds__(1024) void k_scan1(const int* __restrict__ deg,
                                                int* __restrict__ off,
                                                int* __restrict__ bsum) {
    __shared__ int buf[SCHUNK];
    int tid = threadIdx.x;
    int i = blockIdx.x * SCHUNK + tid;
    int v = (i < N_NODES) ? deg[i] : 0;
    buf[tid] = v;
    __syncthreads();
    for (int s = 1; s < SCHUNK; s <<= 1) {
        int a = (tid >= s) ? buf[tid - s] : 0;
        __syncthreads();
        buf[tid] += a;
        __syncthreads();
    }
    if (i < N_NODES) off[i] = buf[tid] - v;
    if (tid == SCHUNK - 1) bsum[blockIdx.x] = buf[tid];
}

__global__ void k_scan2(int* __restrict__ bsum, int* __restrict__ off, int nchunks) {
    if (blockIdx.x == 0 && threadIdx.x == 0) {
        int carry = 0;
        for (int b = 0; b < nchunks; ++b) {
            int t = bsum[b];
            bsum[b] = carry;
            carry += t;
        }
        off[N_NODES] = carry;
    }
}

// scan3 (+ folded sums/cnt zeroing)
__global__ void k_scan3(int* __restrict__ off, const int* __restrict__ bsum,
                        float* __restrict__ sums) {
    int i = blockIdx.x * blockDim.x + threadIdx.x;
    if (i < N_GRAPHS * (HID + 1)) sums[i] = 0.0f;
    if (i < N_NODES) off[i] += bsum[i >> 10];
}

// ---------------------------------------------------------------------------
// place + input-linear, 2:1 role-interleaved: input's dense VALU work hides
// under place's random-store latency.
__global__ __launch_bounds__(256) void k_placein(
        const int* __restrict__ ei, const int* __restrict__ off,
        const int* __restrict__ eslot, int* __restrict__ csr,
        const float* __restrict__ ne, const float* __restrict__ W_in,
        const float* __restrict__ b_in,
        ushort_t* __restrict__ hbhi, ushort_t* __restrict__ hblo) {
    __shared__ float sE[LNB][D_IN];            // 16 KB (input role only)
    int b = blockIdx.x;
    int tid = threadIdx.x;

    if ((b % 3) == 2) {
        // ---- input linear: x = ne @ W_in + b_in ----
        int j = tid & 63, w = tid >> 6;
        int nodeBase = (b / 3) * LNB;
        {
            const float4* g = (const float4*)(ne + (size_t)nodeBase * D_IN);
            float4* l = (float4*)&sE[0][0];
            for (int i = tid; i < LNB * D_IN / 4; i += 256) l[i] = g[i];
        }
        __syncthreads();
        float acc[LR];
#pragma unroll
        for (int r = 0; r < LR; ++r) acc[r] = 0.0f;
#pragma unroll 4
        for (int k = 0; k < D_IN; ++k) {
            float wv = W_in[k * HID + j];
#pragma unroll
            for (int r = 0; r < LR; ++r)
                acc[r] = fmaf(sE[w * LR + r][k], wv, acc[r]);
        }
        float bb = b_in[j];
#pragma unroll
        for (int r = 0; r < LR; ++r) {
            int n = nodeBase + w * LR + r;
            float v = acc[r] + bb;
            ushort_t hi = f2bf(v);
            size_t idx = (size_t)n * HID + j;
            hbhi[idx] = hi;
            hblo[idx] = f2bf(v - b2f(hi));
        }
        return;
    }
    // ---- place: csr[off[d] + eslot[e]] = src ----
    int pb = (b / 3) * 2 + (b % 3);
    int e = pb * 256 + tid;
    int d = ei[N_EDGES + e];
    __builtin_nontemporal_store(ei[e], &csr[off[d] + eslot[e]]);
}

// ---------------------------------------------------------------------------
// CSR gather: one wave per node, 8 neighbor rows in flight (8 lanes x uint4
// = one 128B bf16 row each), 3-step shfl_xor reduce, bf16 output row.
__global__ __launch_bounds__(256) void k_gather(const int* __restrict__ off,
                                                const int* __restrict__ csr,
                                                const ushort_t* __restrict__ hb,
                                                ushort_t* __restrict__ aggb) {
    int t = blockIdx.x * blockDim.x + threadIdx.x;
    int n = t >> 6;
    int lane = t & 63;
    int q = lane >> 3, c = lane & 7;
    int beg = off[n], end = off[n + 1];
    float a[8];
#pragma unroll
    for (int x = 0; x < 8; ++x) a[x] = 0.f;
#pragma unroll 2
    for (int i = beg; i < end; i += 8) {
        int idx = i + q;
        int sidx = csr[min(idx, end - 1)];
        float msk = (idx < end) ? 1.0f : 0.0f;
        uint4 v = *(const uint4*)(hb + (size_t)sidx * HID + c * 8);
        a[0] = fmaf(msk, __uint_as_float(v.x << 16), a[0]);
        a[1] = fmaf(msk, __uint_as_float(v.x & 0xffff0000u), a[1]);
        a[2] = fmaf(msk, __uint_as_float(v.y << 16), a[2]);
        a[3] = fmaf(msk, __uint_as_float(v.y & 0xffff0000u), a[3]);
        a[4] = fmaf(msk, __uint_as_float(v.z << 16), a[4]);
        a[5] = fmaf(msk, __uint_as_float(v.z & 0xffff0000u), a[5]);
        a[6] = fmaf(msk, __uint_as_float(v.w << 16), a[6]);
        a[7] = fmaf(msk, __uint_as_float(v.w & 0xffff0000u), a[7]);
    }
#pragma unroll
    for (int x = 0; x < 8; ++x) {
        a[x] += __shfl_xor(a[x], 8);
        a[x] += __shfl_xor(a[x], 16);
        a[x] += __shfl_xor(a[x], 32);
    }
    if (q == 0) {
        uint4 o;
        o.x = (uint_t)f2bf(a[0]) | ((uint_t)f2bf(a[1]) << 16);
        o.y = (uint_t)f2bf(a[2]) | ((uint_t)f2bf(a[3]) << 16);
        o.z = (uint_t)f2bf(a[4]) | ((uint_t)f2bf(a[5]) << 16);
        o.w = (uint_t)f2bf(a[6]) | ((uint_t)f2bf(a[7]) << 16);
        *(uint4*)(aggb + (size_t)n * HID + c * 8) = o;
    }
}

// ---------------------------------------------------------------------------
// MFMA GRU. State h stored as two bf16 planes (hi + lo residual ~ fp21):
// hidden-side A fragments are direct short8 loads; input side A is bf16 aggb.
// Whi staged in LDS (48 KB).
__global__ __launch_bounds__(256) void k_gru(const ushort_t* __restrict__ aggb,
                                             ushort_t* __restrict__ hbhi,
                                             ushort_t* __restrict__ hblo,
                                             const short* __restrict__ Whi,
                                             const short* __restrict__ Wlo,
                                             const float* __restrict__ b_ih,
                                             const float* __restrict__ b_hh) {
    __shared__ short8 sW[24 * 2 * 64];         // 48 KB
    int tid = threadIdx.x;
    {
        const short8* gW = (const short8*)Whi;
#pragma unroll
        for (int i = 0; i < 12; ++i) sW[tid + i * 256] = gW[tid + i * 256];
    }
    int wv = tid >> 6, l = tid & 63;
    int q = l >> 4, c = l & 15;
    int nodeBase = blockIdx.x * 64 + wv * 16;

    // ---- A fragments: row = lane&15, k = s*32 + q*8 + i ----
    int anode = nodeBase + c;
    int acl = (anode < N_NODES) ? anode : (N_NODES - 1);
    const ushort_t* arow = aggb + (size_t)acl * HID;
    const ushort_t* hrowh = hbhi + (size_t)acl * HID;
    const ushort_t* hrowl = hblo + (size_t)acl * HID;
    short8 Ag[2], Ah_hi[2], Ah_lo[2];
    Ag[0] = *(const short8*)(arow + q * 8);
    Ag[1] = *(const short8*)(arow + 32 + q * 8);
    Ah_hi[0] = *(const short8*)(hrowh + q * 8);
    Ah_hi[1] = *(const short8*)(hrowh + 32 + q * 8);
    Ah_lo[0] = *(const short8*)(hrowl + q * 8);
    Ah_lo[1] = *(const short8*)(hrowl + 32 + q * 8);
    __syncthreads();

    f32x4 acc[24];
    const f32x4 zero = {0.f, 0.f, 0.f, 0.f};
#pragma unroll
    for (int t = 0; t < 24; ++t) acc[t] = zero;

    const short8* BH = sW + l;
    const short8* BL = ((const short8*)Wlo) + l;
#pragma unroll
    for (int t = 0; t < 24; ++t) {
        short8 b0h = BH[(t * 2 + 0) * 64];
        short8 b1h = BH[(t * 2 + 1) * 64];
        short8 b0l = BL[(t * 2 + 0) * 64];
        short8 b1l = BL[(t * 2 + 1) * 64];
        if (t < 12) {
            acc[t] = MFMA(Ag[0], b0h, acc[t]);
            acc[t] = MFMA(Ag[0], b0l, acc[t]);
            acc[t] = MFMA(Ag[1], b1h, acc[t]);
            acc[t] = MFMA(Ag[1], b1l, acc[t]);
        } else {
            acc[t] = MFMA(Ah_hi[0], b0h, acc[t]);
            acc[t] = MFMA(Ah_lo[0], b0h, acc[t]);
            acc[t] = MFMA(Ah_hi[0], b0l, acc[t]);
            acc[t] = MFMA(Ah_hi[1], b1h, acc[t]);
            acc[t] = MFMA(Ah_lo[1], b1h, acc[t]);
            acc[t] = MFMA(Ah_hi[1], b1l, acc[t]);
        }
    }

    // ---- elementwise GRU, lane-local ----
#pragma unroll
    for (int jb = 0; jb < 4; ++jb) {
        int j = jb * 16 + c;
        float br  = b_ih[j] + b_hh[j];
        float bz  = b_ih[64 + j] + b_hh[64 + j];
        float bin = b_ih[128 + j];
        float bhn = b_hh[128 + j];
#pragma unroll
        for (int i = 0; i < 4; ++i) {
            int m = nodeBase + q * 4 + i;
            if (m < N_NODES) {
                float ir = acc[jb][i],      iz = acc[4 + jb][i],  inn = acc[8 + jb][i];
                float hr = acc[12 + jb][i], hz = acc[16 + jb][i], hn = acc[20 + jb][i];
                float rr = fast_sigmoid(ir + hr + br);
                float zz = fast_sigmoid(iz + hz + bz);
                float nv = fast_tanh((inn + bin) + rr * (hn + bhn));
                size_t idx = (size_t)m * HID + j;
                float hold = b2f(hbhi[idx]) + b2f(hblo[idx]);
                float v = (1.0f - zz) * nv + zz * hold;
                ushort_t hi = f2bf(v);
                hbhi[idx] = hi;
                hblo[idx] = f2bf(v - b2f(hi));
            }
        }
    }
}

// ---------------------------------------------------------------------------
// mean-pool from the bf16 hi plane
#define POOL_NPW 32
__global__ void k_pool(const ushort_t* __restrict__ hb,
                       const int* __restrict__ batch,
                       float* __restrict__ sums,
                       float* __restrict__ cntf) {
    int wid = (blockIdx.x * blockDim.x + threadIdx.x) >> 6;
    int j = threadIdx.x & 63;
    int base = wid * POOL_NPW;
    if (base >= N_NODES) return;
    int end = base + POOL_NPW;
    if (end > N_NODES) end = N_NODES;
    float acc = 0.f, c = 0.f;
    int curg = batch[base];
    for (int n = base; n < end; ++n) {
        int g = batch[n];
        if (g != curg) {
            atomicAdd(&sums[(size_t)curg * HID + j], acc);
            if (j == 0) atomicAdd(&cntf[curg], c);
            acc = 0.f; c = 0.f; curg = g;
        }
        acc += b2f(hb[(size_t)n * HID + j]);
        c += 1.f;
    }
    atomicAdd(&sums[(size_t)curg * HID + j], acc);
    if (j == 0) atomicAdd(&cntf[curg], c);
}

__global__ void k_out(const float* __restrict__ sums,
                      const float* __restrict__ cntf,
                      const float* __restrict__ W_out,
                      const float* __restrict__ b_out,
                      float* __restrict__ out) {
    int t = blockIdx.x * blockDim.x + threadIdx.x;
    if (t >= N_GRAPHS * D_OUT) return;
    int g = t / D_OUT, o = t % D_OUT;
    float inv_c = __builtin_amdgcn_rcpf(fmaxf(cntf[g], 1.0f));
    float acc = 0.0f;
#pragma unroll
    for (int k = 0; k < HID; ++k)
        acc = fmaf(sums[g * HID + k], W_out[k * D_OUT + o], acc);
    out[t] = acc * inv_c + b_out[o];
}

// ---------------------------------------------------------------------------
static inline char* align256(char* p) {
    return (char*)(((uintptr_t)p + 255) & ~(uintptr_t)255);
}

extern "C" void kernel_launch(void* const* d_in, const int* in_sizes, int n_in,
                              void* d_out, int out_size, void* d_ws, size_t ws_size,
                              hipStream_t stream) {
    const float* node_embed = (const float*)d_in[0];
    const int*   edge_index = (const int*)  d_in[1];
    const int*   batch      = (const int*)  d_in[2];
    const float* W_in       = (const float*)d_in[3];
    const float* b_in       = (const float*)d_in[4];
    const float* ggnn_w     = (const float*)d_in[5];
    const float* gru_w_ih   = (const float*)d_in[6];
    const float* gru_w_hh   = (const float*)d_in[7];
    const float* gru_b_ih   = (const float*)d_in[8];
    const float* gru_b_hh   = (const float*)d_in[9];
    const float* W_out      = (const float*)d_in[10];
    const float* b_out      = (const float*)d_in[11];
    float* out = (float*)d_out;

    char* p = (char*)d_ws;
    ushort_t* hbhi  = (ushort_t*)p; p = align256(p + (size_t)N_NODES * HID * sizeof(ushort_t));
    ushort_t* hblo  = (ushort_t*)p; p = align256(p + (size_t)N_NODES * HID * sizeof(ushort_t));
    ushort_t* aggb  = (ushort_t*)p; p = align256(p + (size_t)N_NODES * HID * sizeof(ushort_t));
    int*      csr   = (int*)p;      p = align256(p + (size_t)N_EDGES * sizeof(int));
    int*      eslot = (int*)p;      p = align256(p + (size_t)N_EDGES * sizeof(int));
    int*      off   = (int*)p;      p = align256(p + (size_t)(N_NODES + 1) * sizeof(int));
    int*      deg   = (int*)p;      p = align256(p + (size_t)N_NODES * sizeof(int));
    int*      bsum  = (int*)p;      p = align256(p + 256 * sizeof(int));
    short*    Whi   = (short*)p;    p = align256(p + (size_t)N_LAYERS * WSTRIDE * sizeof(short));
    short*    Wlo   = (short*)p;    p = align256(p + (size_t)N_LAYERS * WSTRIDE * sizeof(short));
    float*    sums  = (float*)p;
    float*    cntf  = (float*)(p + (size_t)N_GRAPHS * HID * sizeof(float));

    const int BLK = 256;
    const int nchunks = (N_NODES + SCHUNK - 1) / SCHUNK;

    hipMemsetAsync(deg, 0, (size_t)N_NODES * sizeof(int), stream);

    // hist + weight-prep, interleaved
    k_front<<<HIST_B + PREP_B, BLK, 0, stream>>>(
        edge_index, deg, eslot, ggnn_w, gru_w_ih, gru_w_hh, Whi, Wlo);

    k_scan1<<<nchunks, SCHUNK, 0, stream>>>(deg, off, bsum);
    k_scan2<<<1, 64, 0, stream>>>(bsum, off, nchunks);
    k_scan3<<<(N_NODES + BLK - 1) / BLK, BLK, 0, stream>>>(off, bsum, sums);

    // place + input-linear, interleaved
    k_placein<<<PLACE_B + INPUT_B, BLK, 0, stream>>>(
        edge_index, off, eslot, csr, node_embed, W_in, b_in, hbhi, hblo);

    for (int l = 0; l < N_LAYERS; ++l) {
        k_gather<<<N_NODES * 64 / BLK, BLK, 0, stream>>>(off, csr, hbhi, aggb);
        k_gru<<<(N_NODES + 63) / 64, BLK, 0, stream>>>(
            aggb, hbhi, hblo, Whi + (size_t)l * WSTRIDE, Wlo + (size_t)l * WSTRIDE,
            gru_b_ih, gru_b_hh);
    }

    {
        int waves = (N_NODES + POOL_NPW - 1) / POOL_NPW;
        int threads = waves * 64;
        k_pool<<<(threads + BLK - 1) / BLK, BLK, 0, stream>>>(hbhi, batch, sums, cntf);
    }
    k_out<<<(N_GRAPHS * D_OUT + BLK - 1) / BLK, BLK, 0, stream>>>(sums, cntf, W_out, b_out, out);
}

// Round 11
// 483.343 us; speedup vs baseline: 1.2718x; 1.1321x over previous
//
#include <hip/hip_runtime.h>

#define N_NODES 100000
#define N_EDGES 1600000
#define D_IN 128
#define HID 64
#define N_LAYERS 5
#define D_OUT 32
#define N_GRAPHS 1000

#define LNB 32            // nodes per input-block (4 waves x 8)
#define LR 8              // nodes per thread in input

// bucketed CSR build
#define BSHIFT 7                          // 128 nodes per bucket
#define NBUCK ((N_NODES + 127) >> BSHIFT) // 782
#define CNT_B 256                         // blocks in count/scatter passes
#define EPB (N_EDGES / CNT_B)             // 6250 edges per block slice
#define NT (NBUCK * CNT_B)                // table entries = 200192

typedef unsigned short ushort_t;
typedef unsigned int uint_t;
typedef __attribute__((ext_vector_type(8))) short short8;   // 8 bf16 (4 VGPRs)
typedef __attribute__((ext_vector_type(4))) float f32x4;    // MFMA accumulator

#define MFMA(a, b, c) __builtin_amdgcn_mfma_f32_16x16x32_bf16((a), (b), (c), 0, 0, 0)

// per-layer stride of the prepped weight fragment arrays (in shorts)
#define WSTRIDE (24 * 2 * 64 * 8)

#define INPUT_B (N_NODES / LNB)                     // 3125
#define PREP_B  ((N_LAYERS * WSTRIDE + 255) / 256)  // 480

__device__ __forceinline__ float fast_sigmoid(float x) {
    return __builtin_amdgcn_rcpf(1.0f + __expf(-x));
}
__device__ __forceinline__ float fast_tanh(float x) {
    return 1.0f - 2.0f * __builtin_amdgcn_rcpf(1.0f + __expf(2.0f * x));
}
// fp32 -> bf16 round-to-nearest-even
__device__ __forceinline__ ushort_t f2bf(float f) {
    uint_t u = __float_as_uint(f);
    return (ushort_t)((u + 0x7fffu + ((u >> 16) & 1u)) >> 16);
}
__device__ __forceinline__ float b2f(ushort_t u) {
    return __uint_as_float(((uint_t)u) << 16);
}

// ---------------------------------------------------------------------------
// Pass 1: per-block LDS bucket histograms -> table[bucket][block]
__global__ __launch_bounds__(256) void k_count(const int* __restrict__ ei,
                                               int* __restrict__ table) {
    __shared__ int hcnt[NBUCK];
    int b = blockIdx.x, tid = threadIdx.x;
    for (int i = tid; i < NBUCK; i += 256) hcnt[i] = 0;
    __syncthreads();
    int e0 = b * EPB;
    for (int i = tid; i < EPB; i += 256)
        atomicAdd(&hcnt[ei[N_EDGES + e0 + i] >> BSHIFT], 1);
    __syncthreads();
    for (int i = tid; i < NBUCK; i += 256)
        table[i * CNT_B + b] = hcnt[i];
}

// ---------------------------------------------------------------------------
// Flat exclusive scan over the NT-entry table (3 kernels)
#define SCHUNK 1024
__global__ __launch_bounds__(1024) void k_tscan1(int* __restrict__ table,
                                                 int* __restrict__ bsum) {
    __shared__ int buf[SCHUNK];
    int tid = threadIdx.x;
    int i = blockIdx.x * SCHUNK + tid;
    int v = (i < NT) ? table[i] : 0;
    buf[tid] = v;
    __syncthreads();
    for (int s = 1; s < SCHUNK; s <<= 1) {
        int a = (tid >= s) ? buf[tid - s] : 0;
        __syncthreads();
        buf[tid] += a;
        __syncthreads();
    }
    if (i < NT) table[i] = buf[tid] - v;    // exclusive within chunk
    if (tid == SCHUNK - 1) bsum[blockIdx.x] = buf[tid];
}

// block 0: serial scan of chunk sums; other blocks: zero sums/cnt
__global__ void k_tscan2(int* __restrict__ bsum, int nchunks,
                         float* __restrict__ sums) {
    int b = blockIdx.x;
    if (b == 0) {
        if (threadIdx.x == 0) {
            int carry = 0;
            for (int c = 0; c < nchunks; ++c) {
                int t = bsum[c];
                bsum[c] = carry;
                carry += t;
            }
        }
        return;
    }
    int i = (b - 1) * 256 + threadIdx.x;
    if (i < N_GRAPHS * (HID + 1)) sums[i] = 0.0f;
}

__global__ void k_tscan3(int* __restrict__ table, const int* __restrict__ bsum) {
    int i = blockIdx.x * blockDim.x + threadIdx.x;
    if (i < NT) table[i] += bsum[i >> 10];
}

// ---------------------------------------------------------------------------
// Pass 2 (+ interleaved weight-prep and input-linear):
//   scatter: append each edge (src,dst) to its bucket's per-block run
__global__ __launch_bounds__(256) void k_scatin(
        const int* __restrict__ ei, const int* __restrict__ table,
        uint2* __restrict__ eb,
        const float* __restrict__ ggnn_w, const float* __restrict__ w_ih,
        const float* __restrict__ w_hh,
        short* __restrict__ Whi, short* __restrict__ Wlo,
        const float* __restrict__ ne, const float* __restrict__ W_in,
        const float* __restrict__ b_in,
        ushort_t* __restrict__ hbhi, ushort_t* __restrict__ hblo) {
    __shared__ int cur[NBUCK];
    __shared__ float sE[LNB][D_IN];            // input role only (16 KB)
    int b = blockIdx.x;
    int tid = threadIdx.x;

    if (b < CNT_B) {
        // ---- scatter ----
        for (int i = tid; i < NBUCK; i += 256) cur[i] = table[i * CNT_B + b];
        __syncthreads();
        int e0 = b * EPB;
        for (int i = tid; i < EPB; i += 256) {
            int s = ei[e0 + i];
            int d = ei[N_EDGES + e0 + i];
            int pos = atomicAdd(&cur[d >> BSHIFT], 1);
            uint2 v; v.x = (uint_t)s; v.y = (uint_t)d;
            eb[pos] = v;
        }
        return;
    }
    if (b < CNT_B + PREP_B) {
        // ---- weight prep ----
        int t = (b - CNT_B) * 256 + tid;
        if (t >= N_LAYERS * WSTRIDE) return;
        int i    = t & 7;
        int lane = (t >> 3) & 63;
        int s    = (t >> 9) & 1;
        int tt   = (t >> 10) % 24;
        int lay  = (t >> 10) / 24;
        int k    = s * 32 + (lane >> 4) * 8 + i;
        int col  = tt * 16 + (lane & 15);
        float val;
        if (col < 192) {
            const float* wl = ggnn_w + ((size_t)lay * HID + k) * HID;
            const float* wi = w_ih + (size_t)col * HID;
            float acc = 0.0f;
#pragma unroll 8
            for (int q = 0; q < HID; ++q) acc = fmaf(wl[q], wi[q], acc);
            val = acc;
        } else {
            val = w_hh[(size_t)(col - 192) * HID + k];
        }
        ushort_t h_ = f2bf(val);
        Whi[t] = (short)h_;
        Wlo[t] = (short)f2bf(val - b2f(h_));
        return;
    }
    // ---- input linear: x = ne @ W_in + b_in ----
    int j = tid & 63, w = tid >> 6;
    int nodeBase = (b - CNT_B - PREP_B) * LNB;
    {
        const float4* g = (const float4*)(ne + (size_t)nodeBase * D_IN);
        float4* l = (float4*)&sE[0][0];
        for (int i = tid; i < LNB * D_IN / 4; i += 256) l[i] = g[i];
    }
    __syncthreads();
    float acc[LR];
#pragma unroll
    for (int r = 0; r < LR; ++r) acc[r] = 0.0f;
#pragma unroll 4
    for (int k = 0; k < D_IN; ++k) {
        float wv = W_in[k * HID + j];
#pragma unroll
        for (int r = 0; r < LR; ++r)
            acc[r] = fmaf(sE[w * LR + r][k], wv, acc[r]);
    }
    float bb = b_in[j];
#pragma unroll
    for (int r = 0; r < LR; ++r) {
        int n = nodeBase + w * LR + r;
        float v = acc[r] + bb;
        ushort_t hi = f2bf(v);
        size_t idx = (size_t)n * HID + j;
        hbhi[idx] = hi;
        hblo[idx] = f2bf(v - b2f(hi));
    }
}

// ---------------------------------------------------------------------------
// Pass 3: per-bucket local CSR build (counts, 128-wide scan, place), all LDS
__global__ __launch_bounds__(256) void k_csr(const int* __restrict__ table,
                                             const uint2* __restrict__ eb,
                                             int* __restrict__ csr,
                                             int* __restrict__ off) {
    __shared__ int cnt[128];
    __shared__ int slot[128];
    int b = blockIdx.x, tid = threadIdx.x;
    int nodeBase = b << BSHIFT;
    int nn = min(128, N_NODES - nodeBase);
    int beg = table[b * CNT_B];
    int end = (b == NBUCK - 1) ? N_EDGES : table[(b + 1) * CNT_B];

    if (tid < 128) { cnt[tid] = 0; slot[tid] = 0; }
    __syncthreads();
    for (int i = beg + tid; i < end; i += 256)
        atomicAdd(&cnt[eb[i].y & 127], 1);
    __syncthreads();

    // 128-wide inclusive scan (Hillis-Steele)
    int orig = (tid < 128) ? cnt[tid] : 0;
    for (int s = 1; s < 128; s <<= 1) {
        int a = (tid >= s && tid < 128) ? cnt[tid - s] : 0;
        __syncthreads();
        if (tid < 128) cnt[tid] += a;
        __syncthreads();
    }
    int start = 0;
    if (tid < 128) start = beg + cnt[tid] - orig;   // exclusive + bucket base
    __syncthreads();
    if (tid < 128) {
        cnt[tid] = start;
        if (tid < nn) off[nodeBase + tid] = start;
    }
    if (b == NBUCK - 1 && tid == 0) off[N_NODES] = N_EDGES;
    __syncthreads();

    for (int i = beg + tid; i < end; i += 256) {
        uint2 e = eb[i];
        int ln = e.y & 127;
        int p = cnt[ln] + atomicAdd(&slot[ln], 1);
        csr[p] = (int)e.x;
    }
}

// ---------------------------------------------------------------------------
// CSR gather: one wave per node, 8 neighbor rows in flight (8 lanes x uint4
// = one 128B bf16 row each), 3-step shfl_xor reduce, bf16 output row.
__global__ __launch_bounds__(256) void k_gather(const int* __restrict__ off,
                                                const int* __restrict__ csr,
                                                const ushort_t* __restrict__ hb,
                                                ushort_t* __restrict__ aggb) {
    int t = blockIdx.x * blockDim.x + threadIdx.x;
    int n = t >> 6;
    int lane = t & 63;
    int q = lane >> 3, c = lane & 7;
    int beg = off[n], end = off[n + 1];
    float a[8];
#pragma unroll
    for (int x = 0; x < 8; ++x) a[x] = 0.f;
#pragma unroll 2
    for (int i = beg; i < end; i += 8) {
        int idx = i + q;
        int sidx = csr[min(idx, end - 1)];
        float msk = (idx < end) ? 1.0f : 0.0f;
        uint4 v = *(const uint4*)(hb + (size_t)sidx * HID + c * 8);
        a[0] = fmaf(msk, __uint_as_float(v.x << 16), a[0]);
        a[1] = fmaf(msk, __uint_as_float(v.x & 0xffff0000u), a[1]);
        a[2] = fmaf(msk, __uint_as_float(v.y << 16), a[2]);
        a[3] = fmaf(msk, __uint_as_float(v.y & 0xffff0000u), a[3]);
        a[4] = fmaf(msk, __uint_as_float(v.z << 16), a[4]);
        a[5] = fmaf(msk, __uint_as_float(v.z & 0xffff0000u), a[5]);
        a[6] = fmaf(msk, __uint_as_float(v.w << 16), a[6]);
        a[7] = fmaf(msk, __uint_as_float(v.w & 0xffff0000u), a[7]);
    }
#pragma unroll
    for (int x = 0; x < 8; ++x) {
        a[x] += __shfl_xor(a[x], 8);
        a[x] += __shfl_xor(a[x], 16);
        a[x] += __shfl_xor(a[x], 32);
    }
    if (q == 0) {
        uint4 o;
        o.x = (uint_t)f2bf(a[0]) | ((uint_t)f2bf(a[1]) << 16);
        o.y = (uint_t)f2bf(a[2]) | ((uint_t)f2bf(a[3]) << 16);
        o.z = (uint_t)f2bf(a[4]) | ((uint_t)f2bf(a[5]) << 16);
        o.w = (uint_t)f2bf(a[6]) | ((uint_t)f2bf(a[7]) << 16);
        *(uint4*)(aggb + (size_t)n * HID + c * 8) = o;
    }
}

// ---------------------------------------------------------------------------
// MFMA GRU. State h stored as two bf16 planes (hi + lo residual ~ fp21):
// hidden-side A fragments are direct short8 loads; input side A is bf16 aggb.
// Whi staged in LDS (48 KB).
__global__ __launch_bounds__(256) void k_gru(const ushort_t* __restrict__ aggb,
                                             ushort_t* __restrict__ hbhi,
                                             ushort_t* __restrict__ hblo,
                                             const short* __restrict__ Whi,
                                             const short* __restrict__ Wlo,
                                             const float* __restrict__ b_ih,
                                             const float* __restrict__ b_hh) {
    __shared__ short8 sW[24 * 2 * 64];         // 48 KB
    int tid = threadIdx.x;
    {
        const short8* gW = (const short8*)Whi;
#pragma unroll
        for (int i = 0; i < 12; ++i) sW[tid + i * 256] = gW[tid + i * 256];
    }
    int wv = tid >> 6, l = tid & 63;
    int q = l >> 4, c = l & 15;
    int nodeBase = blockIdx.x * 64 + wv * 16;

    // ---- A fragments: row = lane&15, k = s*32 + q*8 + i ----
    int anode = nodeBase + c;
    int acl = (anode < N_NODES) ? anode : (N_NODES - 1);
    const ushort_t* arow = aggb + (size_t)acl * HID;
    const ushort_t* hrowh = hbhi + (size_t)acl * HID;
    const ushort_t* hrowl = hblo + (size_t)acl * HID;
    short8 Ag[2], Ah_hi[2], Ah_lo[2];
    Ag[0] = *(const short8*)(arow + q * 8);
    Ag[1] = *(const short8*)(arow + 32 + q * 8);
    Ah_hi[0] = *(const short8*)(hrowh + q * 8);
    Ah_hi[1] = *(const short8*)(hrowh + 32 + q * 8);
    Ah_lo[0] = *(const short8*)(hrowl + q * 8);
    Ah_lo[1] = *(const short8*)(hrowl + 32 + q * 8);
    __syncthreads();

    f32x4 acc[24];
    const f32x4 zero = {0.f, 0.f, 0.f, 0.f};
#pragma unroll
    for (int t = 0; t < 24; ++t) acc[t] = zero;

    const short8* BH = sW + l;
    const short8* BL = ((const short8*)Wlo) + l;
#pragma unroll
    for (int t = 0; t < 24; ++t) {
        short8 b0h = BH[(t * 2 + 0) * 64];
        short8 b1h = BH[(t * 2 + 1) * 64];
        short8 b0l = BL[(t * 2 + 0) * 64];
        short8 b1l = BL[(t * 2 + 1) * 64];
        if (t < 12) {
            acc[t] = MFMA(Ag[0], b0h, acc[t]);
            acc[t] = MFMA(Ag[0], b0l, acc[t]);
            acc[t] = MFMA(Ag[1], b1h, acc[t]);
            acc[t] = MFMA(Ag[1], b1l, acc[t]);
        } else {
            acc[t] = MFMA(Ah_hi[0], b0h, acc[t]);
            acc[t] = MFMA(Ah_lo[0], b0h, acc[t]);
            acc[t] = MFMA(Ah_hi[0], b0l, acc[t]);
            acc[t] = MFMA(Ah_hi[1], b1h, acc[t]);
            acc[t] = MFMA(Ah_lo[1], b1h, acc[t]);
            acc[t] = MFMA(Ah_hi[1], b1l, acc[t]);
        }
    }

    // ---- elementwise GRU, lane-local ----
#pragma unroll
    for (int jb = 0; jb < 4; ++jb) {
        int j = jb * 16 + c;
        float br  = b_ih[j] + b_hh[j];
        float bz  = b_ih[64 + j] + b_hh[64 + j];
        float bin = b_ih[128 + j];
        float bhn = b_hh[128 + j];
#pragma unroll
        for (int i = 0; i < 4; ++i) {
            int m = nodeBase + q * 4 + i;
            if (m < N_NODES) {
                float ir = acc[jb][i],      iz = acc[4 + jb][i],  inn = acc[8 + jb][i];
                float hr = acc[12 + jb][i], hz = acc[16 + jb][i], hn = acc[20 + jb][i];
                float rr = fast_sigmoid(ir + hr + br);
                float zz = fast_sigmoid(iz + hz + bz);
                float nv = fast_tanh((inn + bin) + rr * (hn + bhn));
                size_t idx = (size_t)m * HID + j;
                float hold = b2f(hbhi[idx]) + b2f(hblo[idx]);
                float v = (1.0f - zz) * nv + zz * hold;
                ushort_t hi = f2bf(v);
                hbhi[idx] = hi;
                hblo[idx] = f2bf(v - b2f(hi));
            }
        }
    }
}

// ---------------------------------------------------------------------------
// mean-pool from the bf16 hi plane
#define POOL_NPW 32
__global__ void k_pool(const ushort_t* __restrict__ hb,
                       const int* __restrict__ batch,
                       float* __restrict__ sums,
                       float* __restrict__ cntf) {
    int wid = (blockIdx.x * blockDim.x + threadIdx.x) >> 6;
    int j = threadIdx.x & 63;
    int base = wid * POOL_NPW;
    if (base >= N_NODES) return;
    int end = base + POOL_NPW;
    if (end > N_NODES) end = N_NODES;
    float acc = 0.f, c = 0.f;
    int curg = batch[base];
    for (int n = base; n < end; ++n) {
        int g = batch[n];
        if (g != curg) {
            atomicAdd(&sums[(size_t)curg * HID + j], acc);
            if (j == 0) atomicAdd(&cntf[curg], c);
            acc = 0.f; c = 0.f; curg = g;
        }
        acc += b2f(hb[(size_t)n * HID + j]);
        c += 1.f;
    }
    atomicAdd(&sums[(size_t)curg * HID + j], acc);
    if (j == 0) atomicAdd(&cntf[curg], c);
}

__global__ void k_out(const float* __restrict__ sums,
                      const float* __restrict__ cntf,
                      const float* __restrict__ W_out,
                      const float* __restrict__ b_out,
                      float* __restrict__ out) {
    int t = blockIdx.x * blockDim.x + threadIdx.x;
    if (t >= N_GRAPHS * D_OUT) return;
    int g = t / D_OUT, o = t % D_OUT;
    float inv_c = __builtin_amdgcn_rcpf(fmaxf(cntf[g], 1.0f));
    float acc = 0.0f;
#pragma unroll
    for (int k = 0; k < HID; ++k)
        acc = fmaf(sums[g * HID + k], W_out[k * D_OUT + o], acc);
    out[t] = acc * inv_c + b_out[o];
}

// ---------------------------------------------------------------------------
static inline char* align256(char* p) {
    return (char*)(((uintptr_t)p + 255) & ~(uintptr_t)255);
}

extern "C" void kernel_launch(void* const* d_in, const int* in_sizes, int n_in,
                              void* d_out, int out_size, void* d_ws, size_t ws_size,
                              hipStream_t stream) {
    const float* node_embed = (const float*)d_in[0];
    const int*   edge_index = (const int*)  d_in[1];
    const int*   batch      = (const int*)  d_in[2];
    const float* W_in       = (const float*)d_in[3];
    const float* b_in       = (const float*)d_in[4];
    const float* ggnn_w     = (const float*)d_in[5];
    const float* gru_w_ih   = (const float*)d_in[6];
    const float* gru_w_hh   = (const float*)d_in[7];
    const float* gru_b_ih   = (const float*)d_in[8];
    const float* gru_b_hh   = (const float*)d_in[9];
    const float* W_out      = (const float*)d_in[10];
    const float* b_out      = (const float*)d_in[11];
    float* out = (float*)d_out;

    char* p = (char*)d_ws;
    ushort_t* hbhi  = (ushort_t*)p; p = align256(p + (size_t)N_NODES * HID * sizeof(ushort_t));
    ushort_t* hblo  = (ushort_t*)p; p = align256(p + (size_t)N_NODES * HID * sizeof(ushort_t));
    ushort_t* aggb  = (ushort_t*)p; p = align256(p + (size_t)N_NODES * HID * sizeof(ushort_t));
    int*      csr   = (int*)p;      p = align256(p + (size_t)N_EDGES * sizeof(int));
    uint2*    eb    = (uint2*)p;    p = align256(p + (size_t)N_EDGES * sizeof(uint2));
    int*      table = (int*)p;      p = align256(p + (size_t)NT * sizeof(int));
    int*      off   = (int*)p;      p = align256(p + (size_t)(N_NODES + 1) * sizeof(int));
    int*      bsumT = (int*)p;      p = align256(p + 256 * sizeof(int));
    short*    Whi   = (short*)p;    p = align256(p + (size_t)N_LAYERS * WSTRIDE * sizeof(short));
    short*    Wlo   = (short*)p;    p = align256(p + (size_t)N_LAYERS * WSTRIDE * sizeof(short));
    float*    sums  = (float*)p;
    float*    cntf  = (float*)(p + (size_t)N_GRAPHS * HID * sizeof(float));

    const int BLK = 256;
    const int nchunksT = (NT + SCHUNK - 1) / SCHUNK;   // 196

    // bucketed CSR build
    k_count<<<CNT_B, BLK, 0, stream>>>(edge_index, table);
    k_tscan1<<<nchunksT, SCHUNK, 0, stream>>>(table, bsumT);
    k_tscan2<<<1 + (N_GRAPHS * (HID + 1) + BLK - 1) / BLK, BLK, 0, stream>>>(
        bsumT, nchunksT, sums);
    k_tscan3<<<(NT + BLK - 1) / BLK, BLK, 0, stream>>>(table, bsumT);
    // scatter + weight prep + input linear (interleaved roles)
    k_scatin<<<CNT_B + PREP_B + INPUT_B, BLK, 0, stream>>>(
        edge_index, table, eb,
        ggnn_w, gru_w_ih, gru_w_hh, Whi, Wlo,
        node_embed, W_in, b_in, hbhi, hblo);
    k_csr<<<NBUCK, BLK, 0, stream>>>(table, eb, csr, off);

    for (int l = 0; l < N_LAYERS; ++l) {
        k_gather<<<N_NODES * 64 / BLK, BLK, 0, stream>>>(off, csr, hbhi, aggb);
        k_gru<<<(N_NODES + 63) / 64, BLK, 0, stream>>>(
            aggb, hbhi, hblo, Whi + (size_t)l * WSTRIDE, Wlo + (size_t)l * WSTRIDE,
            gru_b_ih, gru_b_hh);
    }

    {
        int waves = (N_NODES + POOL_NPW - 1) / POOL_NPW;
        int threads = waves * 64;
        k_pool<<<(threads + BLK - 1) / BLK, BLK, 0, stream>>>(hbhi, batch, sums, cntf);
    }
    k_out<<<(N_GRAPHS * D_OUT + BLK - 1) / BLK, BLK, 0, stream>>>(sums, cntf, W_out, b_out, out);
}